// Round 4
// baseline (613.343 us; speedup 1.0000x reference)
//
#include <hip/hip_runtime.h>
#include <hip/hip_bf16.h>

// ---- problem constants ----
#define M_IMG 1008
#define N_PCD 1024
#define CDIM  256
#define NI_F  76800
#define NP_F  30000
#define KI    64
#define KP    64
#define NUM_CORR 256
#define NPAIR (NUM_CORR * KI)       // 16384
#define CAND_CAP 4096
#define KEY_MOD 30001u
#define SENT_KEY (76800u * 30001u + 30000u)   // 2,304,106,800 < 2^32

#define NEG_INF (-__builtin_inff())

// bool inputs may arrive as uint8 (numpy bool) or int32 (harness "integer")
// layouts. Detected at runtime; *flag != 0 means uint8.
__device__ __forceinline__ bool mask_val(const void* p, int i, int is_u8) {
    return is_u8 ? (((const unsigned char*)p)[i] != 0)
                 : (((const int*)p)[i] != 0);
}

// Kernel 0: detect bool layout from pcd_knn_msk (65536 elements, ~90% true).
// View first 65536 bytes as 16384 u32 (safe under both layouts).
// u8 layout: upper 3 bytes often nonzero. i32 layout: values 0/1 -> upper 3
// bytes always zero. grid(16)x256, one u32 per thread.
__global__ void detect_bool_kernel(const unsigned int* __restrict__ p,
                                   int* __restrict__ flag) {
    __shared__ int s_cnt;
    if (threadIdx.x == 0) s_cnt = 0;
    __syncthreads();
    unsigned int x = p[blockIdx.x * 256 + threadIdx.x];
    if (x & 0xFFFFFF00u) atomicAdd(&s_cnt, 1);
    __syncthreads();
    if (threadIdx.x == 0 && s_cnt != 0) atomicAdd(flag, 1);
}

// =====================================================================
// Kernel A: coarse sim = img_c @ pcd_c^T, masked to -inf.  grid(16,16)x256
// =====================================================================
__global__ void coarse_sim_kernel(const float* __restrict__ A,   // [1008,256]
                                  const float* __restrict__ B,   // [1024,256]
                                  const void* __restrict__ maskA,
                                  const void* __restrict__ maskB,
                                  const int* __restrict__ flag,
                                  float* __restrict__ sim) {     // [1008,1024]
    __shared__ float sa[64][33];
    __shared__ float sb[64][33];
    const int is_u8 = (*flag != 0);
    const int m0 = blockIdx.y * 64, n0 = blockIdx.x * 64;
    const int tid = threadIdx.x;
    const int ki = tid >> 2;            // row within tile 0..63
    const int kpb = (tid & 3) << 4;     // col group base 0/16/32/48
    float acc[16];
#pragma unroll
    for (int j = 0; j < 16; j++) acc[j] = 0.f;

    for (int cc = 0; cc < CDIM; cc += 32) {
        for (int e = tid; e < 64 * 32; e += 256) {
            int r = e >> 5, c = e & 31;
            int m = m0 + r;
            sa[r][c] = A[(m < M_IMG ? m : 0) * CDIM + cc + c];
            sb[r][c] = B[(n0 + r) * CDIM + cc + c];
        }
        __syncthreads();
#pragma unroll
        for (int c = 0; c < 32; c++) {
            float a = sa[ki][c];
#pragma unroll
            for (int j = 0; j < 16; j++) acc[j] += a * sb[kpb + j][c];
        }
        __syncthreads();
    }
    int m = m0 + ki;
    if (m < M_IMG) {
        bool ma = mask_val(maskA, m, is_u8);
#pragma unroll
        for (int j = 0; j < 16; j++) {
            int n = n0 + kpb + j;
            bool ok = ma && mask_val(maskB, n, is_u8);
            sim[m * N_PCD + n] = ok ? acc[j] : NEG_INF;
        }
    }
}

// ---- top-3 helpers (values only, multiplicity preserved) ----
__device__ __forceinline__ void top3_insert(float v, float& t0, float& t1, float& t2) {
    if (v > t0) { t2 = t1; t1 = t0; t0 = v; }
    else if (v > t1) { t2 = t1; t1 = v; }
    else if (v > t2) { t2 = v; }
}

__device__ __forceinline__ void top3_merge(float a0, float a1, float a2,
                                           float b0, float b1, float b2,
                                           float& x0, float& x1, float& x2) {
    if (a0 >= b0) {
        x0 = a0;
        if (a1 >= b0) { x1 = a1; x2 = (a2 >= b0) ? a2 : b0; }
        else          { x1 = b0; x2 = (a1 >= b1) ? a1 : b1; }
    } else {
        x0 = b0;
        if (b1 >= a0) { x1 = b1; x2 = (b2 >= a0) ? b2 : a0; }
        else          { x1 = a0; x2 = (b1 >= a1) ? b1 : a1; }
    }
}

// =====================================================================
// Kernel B: fused row/col 3rd-largest. grid(1008+16)x256.
// Blocks [0,1008): one row each. Blocks [1008,1024): 64-column stripes,
// coalesced (lane=column, 4 row-groups).
// =====================================================================
__global__ void kth_kernel(const float* __restrict__ sim,
                           float* __restrict__ row_kth,
                           float* __restrict__ col_kth) {
    __shared__ float st[256][3];
    const int tid = threadIdx.x;
    if (blockIdx.x < M_IMG) {
        const float* r = sim + (size_t)blockIdx.x * N_PCD;
        float t0 = NEG_INF, t1 = NEG_INF, t2 = NEG_INF;
        for (int e = tid; e < N_PCD; e += 256) top3_insert(r[e], t0, t1, t2);
        st[tid][0] = t0; st[tid][1] = t1; st[tid][2] = t2;
        __syncthreads();
        for (int s = 128; s > 0; s >>= 1) {
            if (tid < s) {
                float x0, x1, x2;
                top3_merge(st[tid][0], st[tid][1], st[tid][2],
                           st[tid + s][0], st[tid + s][1], st[tid + s][2],
                           x0, x1, x2);
                st[tid][0] = x0; st[tid][1] = x1; st[tid][2] = x2;
            }
            __syncthreads();
        }
        if (tid == 0) row_kth[blockIdx.x] = st[0][2];
    } else {
        const int b2 = blockIdx.x - M_IMG;       // 0..15
        const int c = tid & 63, rr = tid >> 6;   // column lane, row group
        const int col = b2 * 64 + c;
        float t0 = NEG_INF, t1 = NEG_INF, t2 = NEG_INF;
        for (int row = rr; row < M_IMG; row += 4)
            top3_insert(sim[(size_t)row * N_PCD + col], t0, t1, t2);
        st[tid][0] = t0; st[tid][1] = t1; st[tid][2] = t2;
        __syncthreads();
        if (tid < 128) {
            float x0, x1, x2;
            top3_merge(st[tid][0], st[tid][1], st[tid][2],
                       st[tid + 128][0], st[tid + 128][1], st[tid + 128][2],
                       x0, x1, x2);
            st[tid][0] = x0; st[tid][1] = x1; st[tid][2] = x2;
        }
        __syncthreads();
        if (tid < 64) {
            float x0, x1, x2;
            top3_merge(st[tid][0], st[tid][1], st[tid][2],
                       st[tid + 64][0], st[tid + 64][1], st[tid + 64][2],
                       x0, x1, x2);
            col_kth[col] = x2;
        }
    }
}

// Kernel D: compact mutual candidates. grid(4032)x256
__global__ void compact_kernel(const float* __restrict__ sim,
                               const float* __restrict__ row_kth,
                               const float* __restrict__ col_kth,
                               unsigned long long* __restrict__ cand,
                               int* __restrict__ count) {
    int g = blockIdx.x * 256 + threadIdx.x;
    if (g >= M_IMG * N_PCD) return;
    int m = g >> 10, n = g & 1023;
    float v = sim[g];
    if (v > 0.f && v >= row_kth[m] && v >= col_kth[n]) {
        int pos = atomicAdd(count, 1);
        if (pos < CAND_CAP) {
            unsigned int u = __float_as_uint(v);
            unsigned int mono = (u & 0x80000000u) ? ~u : (u | 0x80000000u); // ascending map
            cand[pos] = ((unsigned long long)(~mono) << 32) | (unsigned int)g; // asc sort => val desc, idx asc
        }
    }
}

// =====================================================================
// Kernel E: top-256 selection. Output order is irrelevant (the final out[]
// is a pure function of the selected SET — rank/dedup/score depend only on
// the key multiset), so when K<=256 we skip sorting entirely; otherwise
// bitonic-sort only next_pow2(K) slots. grid(1)x256
// =====================================================================
__global__ void top256_kernel(const unsigned long long* __restrict__ cand,
                              const int* __restrict__ count,
                              int* __restrict__ sel_idx,
                              int* __restrict__ selK) {
    __shared__ unsigned long long s[CAND_CAP];
    int tid = threadIdx.x;
    int K = *count; if (K > CAND_CAP) K = CAND_CAP;
    if (K <= NUM_CORR) {
        if (tid < NUM_CORR) sel_idx[tid] = (tid < K) ? (int)(cand[tid] & 0xFFFFFFFFull) : 0;
        if (tid == 0) *selK = K;
        return;
    }
    int n = 1; while (n < K) n <<= 1;            // 512..4096
    for (int e = tid; e < n; e += 256)
        s[e] = (e < K) ? cand[e] : 0xFFFFFFFFFFFFFFFFull;
    __syncthreads();
    for (int k = 2; k <= n; k <<= 1) {
        for (int j = k >> 1; j > 0; j >>= 1) {
            for (int i = tid; i < n; i += 256) {
                int ij = i ^ j;
                if (ij > i) {
                    bool up = ((i & k) == 0);
                    unsigned long long a = s[i], b = s[ij];
                    if ((a > b) == up) { s[i] = b; s[ij] = a; }
                }
            }
            __syncthreads();
        }
    }
    if (tid < NUM_CORR) sel_idx[tid] = (int)(s[tid] & 0xFFFFFFFFull);
    if (tid == 0) *selK = NUM_CORR;
}

// =====================================================================
// Kernel F: fine matching, one block per correspondence. grid(256)x256
// =====================================================================
__global__ void fine_kernel(const float* __restrict__ img_f,   // [76800,256]
                            const float* __restrict__ pcd_f,   // [30000,256]
                            const int* __restrict__ img_knn,   // [1008,64]
                            const int* __restrict__ pcd_knn,   // [1024,64]
                            const void* __restrict__ pcd_msk,  // [1024,64] bool
                            const int* __restrict__ flag,
                            const int* __restrict__ sel_idx,
                            const int* __restrict__ selK_ptr,
                            unsigned int* __restrict__ keys) { // [16384]
    const int ci = blockIdx.x, tid = threadIdx.x;
    const int selK = *selK_ptr;
    if (ci >= selK) {
        if (tid < KI) keys[ci * KI + tid] = SENT_KEY;
        return;
    }
    __shared__ int s_ik[KI], s_pk[KP];
    __shared__ unsigned char s_mk[KP];
    __shared__ float s_a[64][33], s_b[64][33];
    __shared__ float s_sim[64][65];
    __shared__ int s_rb[64], s_cb[64];
    __shared__ float s_rv[64];

    int flat = sel_idx[ci];
    int gi = flat >> 10, pi = flat & 1023;
    if (tid < 64) {
        const int is_u8 = (*flag != 0);
        s_ik[tid] = img_knn[gi * KI + tid];
        s_pk[tid] = pcd_knn[pi * KP + tid];
        s_mk[tid] = mask_val(pcd_msk, pi * KP + tid, is_u8) ? 1 : 0;
    }
    __syncthreads();

    const int ki = tid >> 2, kpb = (tid & 3) << 4;
    float acc[16];
#pragma unroll
    for (int j = 0; j < 16; j++) acc[j] = 0.f;

    for (int cc = 0; cc < CDIM; cc += 32) {
        for (int e = tid; e < 64 * 32; e += 256) {
            int r = e >> 5, c = e & 31;
            s_a[r][c] = img_f[(size_t)s_ik[r] * CDIM + cc + c];
            s_b[r][c] = pcd_f[(size_t)s_pk[r] * CDIM + cc + c];
        }
        __syncthreads();
#pragma unroll
        for (int c = 0; c < 32; c++) {
            float a = s_a[ki][c];
#pragma unroll
            for (int j = 0; j < 16; j++) acc[j] += a * s_b[kpb + j][c];
        }
        __syncthreads();
    }
#pragma unroll
    for (int j = 0; j < 16; j++) {
        int kp = kpb + j;
        s_sim[ki][kp] = (s_mk[kp] != 0) ? acc[j] : NEG_INF;
    }
    __syncthreads();

    if (tid < 64) {              // row argmax over kp (first-max semantics)
        float best = NEG_INF; int bi = 0;
        for (int kp = 0; kp < 64; kp++) {
            float v = s_sim[tid][kp];
            if (v > best) { best = v; bi = kp; }
        }
        s_rb[tid] = bi; s_rv[tid] = best;
    } else if (tid < 128) {      // col argmax over ki
        int kp = tid - 64;
        float best = NEG_INF; int bi = 0;
        for (int k2 = 0; k2 < 64; k2++) {
            float v = s_sim[k2][kp];
            if (v > best) { best = v; bi = k2; }
        }
        s_cb[kp] = bi;
    }
    __syncthreads();

    if (tid < 64) {
        int rb = s_rb[tid];
        float rv = s_rv[tid];
        bool sel = (s_cb[rb] == tid) && (rv > 0.f);   // mutual top-1 + finite + >FINE_THR
        unsigned int key = sel
            ? ((unsigned int)s_ik[tid] * KEY_MOD + (unsigned int)s_pk[rb])
            : SENT_KEY;
        keys[ci * KI + tid] = key;
    }
}

// =====================================================================
// Kernel G1: chunked rank partial counts. grid(64 my, 64 other)x256.
// cnt[i] += (less<<16) | eq_before  (packed u32; field totals < 2^16)
// =====================================================================
__global__ void rank_count_kernel(const unsigned int* __restrict__ keys,
                                  unsigned int* __restrict__ cnt) {
    __shared__ unsigned int s_k[256];
    const int tid = threadIdx.x;
    const int bi = blockIdx.x, bj = blockIdx.y;
    const int i = bi * 256 + tid;
    const unsigned int myKey = keys[i];
    s_k[tid] = keys[bj * 256 + tid];
    __syncthreads();

    unsigned int less = 0, eqb = 0;
    if (bj < bi) {
#pragma unroll 8
        for (int j = 0; j < 256; j++) {
            unsigned int k = s_k[j];
            less += (k < myKey);
            eqb += (k == myKey);
        }
    } else if (bj == bi) {
#pragma unroll 8
        for (int j = 0; j < 256; j++) {
            unsigned int k = s_k[j];
            less += (k < myKey);
            eqb += (k == myKey) & (j < tid);
        }
    } else {
#pragma unroll 8
        for (int j = 0; j < 256; j++) {
            unsigned int k = s_k[j];
            less += (k < myKey);
        }
    }
    atomicAdd(&cnt[i], (less << 16) | eqb);
}

// Kernel G2: unpack rank, first-occurrence; write scored output. grid(64)x256
__global__ void rank_out_kernel(const unsigned int* __restrict__ keys,
                                const unsigned int* __restrict__ cnt,
                                const float* __restrict__ img_f,
                                const float* __restrict__ pcd_f,
                                float* __restrict__ out) {
    const int i = blockIdx.x * 256 + threadIdx.x;
    const unsigned int myKey = keys[i];
    const unsigned int v = cnt[i];
    const int rank = (int)(v >> 16) + (int)(v & 0xFFFFu);
    unsigned int ic = myKey / KEY_MOD;
    unsigned int pc = myKey - ic * KEY_MOD;
    float score = 0.f;
    if ((v & 0xFFFFu) == 0 && ic < (unsigned)NI_F) {
        const float4* a = (const float4*)(img_f + (size_t)ic * CDIM);
        const float4* b = (const float4*)(pcd_f + (size_t)pc * CDIM);
        float s = 0.f;
#pragma unroll 4
        for (int c = 0; c < CDIM / 4; c++) {
            float4 x = a[c], y = b[c];
            s += x.x * y.x + x.y * y.y + x.z * y.z + x.w * y.w;
        }
        score = s;
    }
    out[rank] = score;
}

// =====================================================================
extern "C" void kernel_launch(void* const* d_in, const int* in_sizes, int n_in,
                              void* d_out, int out_size, void* d_ws, size_t ws_size,
                              hipStream_t stream) {
    const float* img_c = (const float*)d_in[0];
    const float* pcd_c = (const float*)d_in[1];
    const float* img_f = (const float*)d_in[2];
    const float* pcd_f = (const float*)d_in[3];
    const void* img_mask = d_in[4];
    const void* pcd_mask = d_in[5];
    const int* img_knn = (const int*)d_in[6];
    const int* pcd_knn = (const int*)d_in[7];
    const void* pcd_knn_msk = d_in[8];
    float* out = (float*)d_out;

    // ---- workspace layout ----
    char* w = (char*)d_ws;
    size_t off = 0;
    float* sim = (float*)(w + off);            off += (size_t)M_IMG * N_PCD * 4; // 4,128,768
    float* row_kth = (float*)(w + off);        off += M_IMG * 4;
    float* col_kth = (float*)(w + off);        off += N_PCD * 4;
    int* count = (int*)(w + off);              off += 4;
    int* selK = (int*)(w + off);               off += 4;
    int* boolflag = (int*)(w + off);           off += 4;
    off = (off + 7) & ~(size_t)7;
    unsigned long long* cand = (unsigned long long*)(w + off); off += CAND_CAP * 8;
    int* sel_idx = (int*)(w + off);            off += NUM_CORR * 4;
    unsigned int* keys = (unsigned int*)(w + off); off += NPAIR * 4;
    unsigned int* cnt = (unsigned int*)(w + off);  off += NPAIR * 4;

    hipMemsetAsync(count, 0, 12, stream);      // zero count + selK + boolflag
    hipMemsetAsync(cnt, 0, NPAIR * 4, stream); // zero rank counters

    detect_bool_kernel<<<16, 256, 0, stream>>>((const unsigned int*)pcd_knn_msk, boolflag);
    coarse_sim_kernel<<<dim3(16, 16), 256, 0, stream>>>(img_c, pcd_c, img_mask, pcd_mask,
                                                        boolflag, sim);
    kth_kernel<<<M_IMG + 16, 256, 0, stream>>>(sim, row_kth, col_kth);
    compact_kernel<<<(M_IMG * N_PCD) / 256, 256, 0, stream>>>(sim, row_kth, col_kth, cand, count);
    top256_kernel<<<1, 256, 0, stream>>>(cand, count, sel_idx, selK);
    fine_kernel<<<NUM_CORR, 256, 0, stream>>>(img_f, pcd_f, img_knn, pcd_knn, pcd_knn_msk,
                                              boolflag, sel_idx, selK, keys);
    rank_count_kernel<<<dim3(64, 64), 256, 0, stream>>>(keys, cnt);
    rank_out_kernel<<<NPAIR / 256, 256, 0, stream>>>(keys, cnt, img_f, pcd_f, out);
}

// Round 5
// 478.863 us; speedup vs baseline: 1.2808x; 1.2808x over previous
//
#include <hip/hip_runtime.h>
#include <hip/hip_bf16.h>

// ---- problem constants ----
#define M_IMG 1008
#define N_PCD 1024
#define CDIM  256
#define NI_F  76800
#define NP_F  30000
#define KI    64
#define KP    64
#define NUM_CORR 256
#define NPAIR (NUM_CORR * KI)       // 16384
#define CAND_CAP 4096
#define KEY_MOD 30001u
#define SENT_KEY (76800u * 30001u + 30000u)   // 2,304,106,800 < 2^32

#define NEG_INF (-__builtin_inff())

// bool inputs may arrive as uint8 (numpy bool) or int32 (harness "integer")
// layouts. Detected at runtime; *flag != 0 means uint8.
__device__ __forceinline__ bool mask_val(const void* p, int i, int is_u8) {
    return is_u8 ? (((const unsigned char*)p)[i] != 0)
                 : (((const int*)p)[i] != 0);
}

// Kernel 0: detect bool layout from pcd_knn_msk (65536 elements, ~90% true).
// View first 65536 bytes as 16384 u32 (safe under both layouts).
// u8 layout: upper 3 bytes often nonzero. i32 layout: values 0/1 -> upper 3
// bytes always zero. grid(16)x256, one u32 per thread.
__global__ void detect_bool_kernel(const unsigned int* __restrict__ p,
                                   int* __restrict__ flag) {
    __shared__ int s_cnt;
    if (threadIdx.x == 0) s_cnt = 0;
    __syncthreads();
    unsigned int x = p[blockIdx.x * 256 + threadIdx.x];
    if (x & 0xFFFFFF00u) atomicAdd(&s_cnt, 1);
    __syncthreads();
    if (threadIdx.x == 0 && s_cnt != 0) atomicAdd(flag, 1);
}

// =====================================================================
// Kernel A: coarse sim = img_c @ pcd_c^T, masked to -inf.  grid(16,16)x256
// =====================================================================
__global__ void coarse_sim_kernel(const float* __restrict__ A,   // [1008,256]
                                  const float* __restrict__ B,   // [1024,256]
                                  const void* __restrict__ maskA,
                                  const void* __restrict__ maskB,
                                  const int* __restrict__ flag,
                                  float* __restrict__ sim) {     // [1008,1024]
    __shared__ float sa[64][33];
    __shared__ float sb[64][33];
    const int is_u8 = (*flag != 0);
    const int m0 = blockIdx.y * 64, n0 = blockIdx.x * 64;
    const int tid = threadIdx.x;
    const int ki = tid >> 2;            // row within tile 0..63
    const int kpb = (tid & 3) << 4;     // col group base 0/16/32/48
    float acc[16];
#pragma unroll
    for (int j = 0; j < 16; j++) acc[j] = 0.f;

    for (int cc = 0; cc < CDIM; cc += 32) {
        for (int e = tid; e < 64 * 32; e += 256) {
            int r = e >> 5, c = e & 31;
            int m = m0 + r;
            sa[r][c] = A[(m < M_IMG ? m : 0) * CDIM + cc + c];
            sb[r][c] = B[(n0 + r) * CDIM + cc + c];
        }
        __syncthreads();
#pragma unroll
        for (int c = 0; c < 32; c++) {
            float a = sa[ki][c];
#pragma unroll
            for (int j = 0; j < 16; j++) acc[j] += a * sb[kpb + j][c];
        }
        __syncthreads();
    }
    int m = m0 + ki;
    if (m < M_IMG) {
        bool ma = mask_val(maskA, m, is_u8);
#pragma unroll
        for (int j = 0; j < 16; j++) {
            int n = n0 + kpb + j;
            bool ok = ma && mask_val(maskB, n, is_u8);
            sim[m * N_PCD + n] = ok ? acc[j] : NEG_INF;
        }
    }
}

// ---- top-3 helpers (values only, multiplicity preserved) ----
__device__ __forceinline__ void top3_insert(float v, float& t0, float& t1, float& t2) {
    if (v > t0) { t2 = t1; t1 = t0; t0 = v; }
    else if (v > t1) { t2 = t1; t1 = v; }
    else if (v > t2) { t2 = v; }
}

__device__ __forceinline__ void top3_merge(float a0, float a1, float a2,
                                           float b0, float b1, float b2,
                                           float& x0, float& x1, float& x2) {
    if (a0 >= b0) {
        x0 = a0;
        if (a1 >= b0) { x1 = a1; x2 = (a2 >= b0) ? a2 : b0; }
        else          { x1 = b0; x2 = (a1 >= b1) ? a1 : b1; }
    } else {
        x0 = b0;
        if (b1 >= a0) { x1 = b1; x2 = (b2 >= a0) ? b2 : a0; }
        else          { x1 = a0; x2 = (b1 >= a1) ? b1 : a1; }
    }
}

// =====================================================================
// Kernel B: fused row/col 3rd-largest. grid(1008+16)x256.
// Blocks [0,1008): one row each. Blocks [1008,1024): 64-column stripes,
// coalesced (lane=column, 4 row-groups), unrolled for load-latency overlap.
// =====================================================================
__global__ void kth_kernel(const float* __restrict__ sim,
                           float* __restrict__ row_kth,
                           float* __restrict__ col_kth) {
    __shared__ float st[256][3];
    const int tid = threadIdx.x;
    if (blockIdx.x < M_IMG) {
        const float* r = sim + (size_t)blockIdx.x * N_PCD;
        float t0 = NEG_INF, t1 = NEG_INF, t2 = NEG_INF;
#pragma unroll
        for (int e = 0; e < 4; e++) top3_insert(r[e * 256 + tid], t0, t1, t2);
        st[tid][0] = t0; st[tid][1] = t1; st[tid][2] = t2;
        __syncthreads();
        for (int s = 128; s > 0; s >>= 1) {
            if (tid < s) {
                float x0, x1, x2;
                top3_merge(st[tid][0], st[tid][1], st[tid][2],
                           st[tid + s][0], st[tid + s][1], st[tid + s][2],
                           x0, x1, x2);
                st[tid][0] = x0; st[tid][1] = x1; st[tid][2] = x2;
            }
            __syncthreads();
        }
        if (tid == 0) row_kth[blockIdx.x] = st[0][2];
    } else {
        const int b2 = blockIdx.x - M_IMG;       // 0..15
        const int c = tid & 63, rr = tid >> 6;   // column lane, row group
        const int col = b2 * 64 + c;
        float t0 = NEG_INF, t1 = NEG_INF, t2 = NEG_INF;
#pragma unroll 8
        for (int row = rr; row < M_IMG; row += 4)
            top3_insert(sim[(size_t)row * N_PCD + col], t0, t1, t2);
        st[tid][0] = t0; st[tid][1] = t1; st[tid][2] = t2;
        __syncthreads();
        if (tid < 128) {
            float x0, x1, x2;
            top3_merge(st[tid][0], st[tid][1], st[tid][2],
                       st[tid + 128][0], st[tid + 128][1], st[tid + 128][2],
                       x0, x1, x2);
            st[tid][0] = x0; st[tid][1] = x1; st[tid][2] = x2;
        }
        __syncthreads();
        if (tid < 64) {
            float x0, x1, x2;
            top3_merge(st[tid][0], st[tid][1], st[tid][2],
                       st[tid + 64][0], st[tid + 64][1], st[tid + 64][2],
                       x0, x1, x2);
            col_kth[col] = x2;
        }
    }
}

// Kernel D: compact mutual candidates. grid(4032)x256
__global__ void compact_kernel(const float* __restrict__ sim,
                               const float* __restrict__ row_kth,
                               const float* __restrict__ col_kth,
                               unsigned long long* __restrict__ cand,
                               int* __restrict__ count) {
    int g = blockIdx.x * 256 + threadIdx.x;
    if (g >= M_IMG * N_PCD) return;
    int m = g >> 10, n = g & 1023;
    float v = sim[g];
    if (v > 0.f && v >= row_kth[m] && v >= col_kth[n]) {
        int pos = atomicAdd(count, 1);
        if (pos < CAND_CAP) {
            unsigned int u = __float_as_uint(v);
            unsigned int mono = (u & 0x80000000u) ? ~u : (u | 0x80000000u); // ascending map
            cand[pos] = ((unsigned long long)(~mono) << 32) | (unsigned int)g; // asc sort => val desc, idx asc
        }
    }
}

// =====================================================================
// Kernel E1: candidate rank via counting (keys are UNIQUE: distinct flat
// idx in low 32 bits => rank is an exact permutation; ascending packed key
// = (value desc, idx asc), matching lax.top_k tie-break). grid(16,16)x256.
// =====================================================================
__global__ void cand_rank_kernel(const unsigned long long* __restrict__ cand,
                                 const int* __restrict__ count,
                                 unsigned int* __restrict__ cnt2) {
    __shared__ unsigned long long s_k[256];
    const int tid = threadIdx.x;
    int K = *count; if (K > CAND_CAP) K = CAND_CAP;
    const int j0 = blockIdx.y * 256;
    if (j0 >= K) return;                        // uniform: whole chunk empty
    int j = j0 + tid;
    s_k[tid] = (j < K) ? cand[j] : 0xFFFFFFFFFFFFFFFFull;
    __syncthreads();
    const int i = blockIdx.x * 256 + tid;
    if (i >= K) return;
    const unsigned long long my = cand[i];
    unsigned int less = 0;
#pragma unroll 8
    for (int t = 0; t < 256; t++) less += (s_k[t] < my);
    if (less) atomicAdd(&cnt2[i], less);
}

// Kernel E2: select rank<256 into sel_idx (order irrelevant: final out[]
// depends only on the selected SET). grid(16)x256.
__global__ void cand_select_kernel(const unsigned long long* __restrict__ cand,
                                   const int* __restrict__ count,
                                   const unsigned int* __restrict__ cnt2,
                                   int* __restrict__ sel_idx,
                                   int* __restrict__ selK) {
    int K = *count; if (K > CAND_CAP) K = CAND_CAP;
    const int i = blockIdx.x * 256 + threadIdx.x;
    if (i == 0) *selK = (K < NUM_CORR) ? K : NUM_CORR;
    if (i < K) {
        unsigned int r = cnt2[i];
        if (r < NUM_CORR) sel_idx[r] = (int)(cand[i] & 0xFFFFFFFFull);
    }
}

// =====================================================================
// Kernel F: fine matching, one block per correspondence. grid(256)x256
// =====================================================================
__global__ void fine_kernel(const float* __restrict__ img_f,   // [76800,256]
                            const float* __restrict__ pcd_f,   // [30000,256]
                            const int* __restrict__ img_knn,   // [1008,64]
                            const int* __restrict__ pcd_knn,   // [1024,64]
                            const void* __restrict__ pcd_msk,  // [1024,64] bool
                            const int* __restrict__ flag,
                            const int* __restrict__ sel_idx,
                            const int* __restrict__ selK_ptr,
                            unsigned int* __restrict__ keys) { // [16384]
    const int ci = blockIdx.x, tid = threadIdx.x;
    const int selK = *selK_ptr;
    if (ci >= selK) {
        if (tid < KI) keys[ci * KI + tid] = SENT_KEY;
        return;
    }
    __shared__ int s_ik[KI], s_pk[KP];
    __shared__ unsigned char s_mk[KP];
    __shared__ float s_a[64][33], s_b[64][33];
    __shared__ float s_sim[64][65];
    __shared__ int s_rb[64], s_cb[64];
    __shared__ float s_rv[64];

    int flat = sel_idx[ci];
    int gi = flat >> 10, pi = flat & 1023;
    if (tid < 64) {
        const int is_u8 = (*flag != 0);
        s_ik[tid] = img_knn[gi * KI + tid];
        s_pk[tid] = pcd_knn[pi * KP + tid];
        s_mk[tid] = mask_val(pcd_msk, pi * KP + tid, is_u8) ? 1 : 0;
    }
    __syncthreads();

    const int ki = tid >> 2, kpb = (tid & 3) << 4;
    float acc[16];
#pragma unroll
    for (int j = 0; j < 16; j++) acc[j] = 0.f;

    for (int cc = 0; cc < CDIM; cc += 32) {
        for (int e = tid; e < 64 * 32; e += 256) {
            int r = e >> 5, c = e & 31;
            s_a[r][c] = img_f[(size_t)s_ik[r] * CDIM + cc + c];
            s_b[r][c] = pcd_f[(size_t)s_pk[r] * CDIM + cc + c];
        }
        __syncthreads();
#pragma unroll
        for (int c = 0; c < 32; c++) {
            float a = s_a[ki][c];
#pragma unroll
            for (int j = 0; j < 16; j++) acc[j] += a * s_b[kpb + j][c];
        }
        __syncthreads();
    }
#pragma unroll
    for (int j = 0; j < 16; j++) {
        int kp = kpb + j;
        s_sim[ki][kp] = (s_mk[kp] != 0) ? acc[j] : NEG_INF;
    }
    __syncthreads();

    if (tid < 64) {              // row argmax over kp (first-max semantics)
        float best = NEG_INF; int bi = 0;
        for (int kp = 0; kp < 64; kp++) {
            float v = s_sim[tid][kp];
            if (v > best) { best = v; bi = kp; }
        }
        s_rb[tid] = bi; s_rv[tid] = best;
    } else if (tid < 128) {      // col argmax over ki
        int kp = tid - 64;
        float best = NEG_INF; int bi = 0;
        for (int k2 = 0; k2 < 64; k2++) {
            float v = s_sim[k2][kp];
            if (v > best) { best = v; bi = k2; }
        }
        s_cb[kp] = bi;
    }
    __syncthreads();

    if (tid < 64) {
        int rb = s_rb[tid];
        float rv = s_rv[tid];
        bool sel = (s_cb[rb] == tid) && (rv > 0.f);   // mutual top-1 + finite + >FINE_THR
        unsigned int key = sel
            ? ((unsigned int)s_ik[tid] * KEY_MOD + (unsigned int)s_pk[rb])
            : SENT_KEY;
        keys[ci * KI + tid] = key;
    }
}

// =====================================================================
// Kernel G1: chunked rank partial counts. grid(64 my, 64 other)x256.
// cnt[i] += (less<<16) | eq_before  (packed u32; field totals < 2^16)
// =====================================================================
__global__ void rank_count_kernel(const unsigned int* __restrict__ keys,
                                  unsigned int* __restrict__ cnt) {
    __shared__ unsigned int s_k[256];
    const int tid = threadIdx.x;
    const int bi = blockIdx.x, bj = blockIdx.y;
    const int i = bi * 256 + tid;
    const unsigned int myKey = keys[i];
    s_k[tid] = keys[bj * 256 + tid];
    __syncthreads();

    unsigned int less = 0, eqb = 0;
    if (bj < bi) {
#pragma unroll 8
        for (int j = 0; j < 256; j++) {
            unsigned int k = s_k[j];
            less += (k < myKey);
            eqb += (k == myKey);
        }
    } else if (bj == bi) {
#pragma unroll 8
        for (int j = 0; j < 256; j++) {
            unsigned int k = s_k[j];
            less += (k < myKey);
            eqb += (k == myKey) & (j < tid);
        }
    } else {
#pragma unroll 8
        for (int j = 0; j < 256; j++) {
            unsigned int k = s_k[j];
            less += (k < myKey);
        }
    }
    atomicAdd(&cnt[i], (less << 16) | eqb);
}

// Kernel G2: unpack rank, first-occurrence; write scored output. grid(64)x256
__global__ void rank_out_kernel(const unsigned int* __restrict__ keys,
                                const unsigned int* __restrict__ cnt,
                                const float* __restrict__ img_f,
                                const float* __restrict__ pcd_f,
                                float* __restrict__ out) {
    const int i = blockIdx.x * 256 + threadIdx.x;
    const unsigned int myKey = keys[i];
    const unsigned int v = cnt[i];
    const int rank = (int)(v >> 16) + (int)(v & 0xFFFFu);
    unsigned int ic = myKey / KEY_MOD;
    unsigned int pc = myKey - ic * KEY_MOD;
    float score = 0.f;
    if ((v & 0xFFFFu) == 0 && ic < (unsigned)NI_F) {
        const float4* a = (const float4*)(img_f + (size_t)ic * CDIM);
        const float4* b = (const float4*)(pcd_f + (size_t)pc * CDIM);
        float s = 0.f;
#pragma unroll 4
        for (int c = 0; c < CDIM / 4; c++) {
            float4 x = a[c], y = b[c];
            s += x.x * y.x + x.y * y.y + x.z * y.z + x.w * y.w;
        }
        score = s;
    }
    out[rank] = score;
}

// =====================================================================
extern "C" void kernel_launch(void* const* d_in, const int* in_sizes, int n_in,
                              void* d_out, int out_size, void* d_ws, size_t ws_size,
                              hipStream_t stream) {
    const float* img_c = (const float*)d_in[0];
    const float* pcd_c = (const float*)d_in[1];
    const float* img_f = (const float*)d_in[2];
    const float* pcd_f = (const float*)d_in[3];
    const void* img_mask = d_in[4];
    const void* pcd_mask = d_in[5];
    const int* img_knn = (const int*)d_in[6];
    const int* pcd_knn = (const int*)d_in[7];
    const void* pcd_knn_msk = d_in[8];
    float* out = (float*)d_out;

    // ---- workspace layout ----
    char* w = (char*)d_ws;
    size_t off = 0;
    float* sim = (float*)(w + off);            off += (size_t)M_IMG * N_PCD * 4; // 4,128,768
    float* row_kth = (float*)(w + off);        off += M_IMG * 4;
    float* col_kth = (float*)(w + off);        off += N_PCD * 4;
    int* count = (int*)(w + off);              off += 4;
    int* selK = (int*)(w + off);               off += 4;
    int* boolflag = (int*)(w + off);           off += 4;
    off = (off + 7) & ~(size_t)7;
    unsigned long long* cand = (unsigned long long*)(w + off); off += CAND_CAP * 8;
    int* sel_idx = (int*)(w + off);            off += NUM_CORR * 4;
    unsigned int* keys = (unsigned int*)(w + off); off += NPAIR * 4;
    unsigned int* cnt = (unsigned int*)(w + off);  off += NPAIR * 4;   // dedup ranks
    unsigned int* cnt2 = (unsigned int*)(w + off); off += CAND_CAP * 4; // cand ranks

    hipMemsetAsync(count, 0, 12, stream);                        // count + selK + boolflag
    hipMemsetAsync(cnt, 0, (NPAIR + CAND_CAP) * 4, stream);      // cnt + cnt2 (contiguous)

    detect_bool_kernel<<<16, 256, 0, stream>>>((const unsigned int*)pcd_knn_msk, boolflag);
    coarse_sim_kernel<<<dim3(16, 16), 256, 0, stream>>>(img_c, pcd_c, img_mask, pcd_mask,
                                                        boolflag, sim);
    kth_kernel<<<M_IMG + 16, 256, 0, stream>>>(sim, row_kth, col_kth);
    compact_kernel<<<(M_IMG * N_PCD) / 256, 256, 0, stream>>>(sim, row_kth, col_kth, cand, count);
    cand_rank_kernel<<<dim3(16, 16), 256, 0, stream>>>(cand, count, cnt2);
    cand_select_kernel<<<16, 256, 0, stream>>>(cand, count, cnt2, sel_idx, selK);
    fine_kernel<<<NUM_CORR, 256, 0, stream>>>(img_f, pcd_f, img_knn, pcd_knn, pcd_knn_msk,
                                              boolflag, sel_idx, selK, keys);
    rank_count_kernel<<<dim3(64, 64), 256, 0, stream>>>(keys, cnt);
    rank_out_kernel<<<NPAIR / 256, 256, 0, stream>>>(keys, cnt, img_f, pcd_f, out);
}

// Round 6
// 381.980 us; speedup vs baseline: 1.6057x; 1.2536x over previous
//
#include <hip/hip_runtime.h>
#include <hip/hip_bf16.h>

// ---- problem constants ----
#define M_IMG 1008
#define N_PCD 1024
#define CDIM  256
#define NI_F  76800
#define NP_F  30000
#define KI    64
#define KP    64
#define NUM_CORR 256
#define NPAIR (NUM_CORR * KI)       // 16384
#define CAND_CAP 4096
#define KEY_MOD 30001u
#define SENT_KEY (76800u * 30001u + 30000u)   // 2,304,106,800 < 2^32

#define NCHUNK 21                   // 21 row-chunks x 48 rows = 1008
#define NEG_INF (-__builtin_inff())

// bool inputs may arrive as uint8 (numpy bool) or int32 (harness "integer")
// layouts. Detected at runtime; *flag != 0 means uint8.
__device__ __forceinline__ bool mask_val(const void* p, int i, int is_u8) {
    return is_u8 ? (((const unsigned char*)p)[i] != 0)
                 : (((const int*)p)[i] != 0);
}

// Kernel 0: detect bool layout from pcd_knn_msk (65536 elements, ~90% true).
// u8 layout: upper 3 bytes of a u32 view often nonzero; i32 0/1 layout: never.
__global__ void detect_bool_kernel(const unsigned int* __restrict__ p,
                                   int* __restrict__ flag) {
    __shared__ int s_cnt;
    if (threadIdx.x == 0) s_cnt = 0;
    __syncthreads();
    unsigned int x = p[blockIdx.x * 256 + threadIdx.x];
    if (x & 0xFFFFFF00u) atomicAdd(&s_cnt, 1);
    __syncthreads();
    if (threadIdx.x == 0 && s_cnt != 0) atomicAdd(flag, 1);
}

// =====================================================================
// Kernel A: coarse sim = img_c @ pcd_c^T, masked to -inf.  grid(16,16)x256
// =====================================================================
__global__ void coarse_sim_kernel(const float* __restrict__ A,   // [1008,256]
                                  const float* __restrict__ B,   // [1024,256]
                                  const void* __restrict__ maskA,
                                  const void* __restrict__ maskB,
                                  const int* __restrict__ flag,
                                  float* __restrict__ sim) {     // [1008,1024]
    __shared__ float sa[64][33];
    __shared__ float sb[64][33];
    const int is_u8 = (*flag != 0);
    const int m0 = blockIdx.y * 64, n0 = blockIdx.x * 64;
    const int tid = threadIdx.x;
    const int ki = tid >> 2;            // row within tile 0..63
    const int kpb = (tid & 3) << 4;     // col group base 0/16/32/48
    float acc[16];
#pragma unroll
    for (int j = 0; j < 16; j++) acc[j] = 0.f;

    for (int cc = 0; cc < CDIM; cc += 32) {
        for (int e = tid; e < 64 * 32; e += 256) {
            int r = e >> 5, c = e & 31;
            int m = m0 + r;
            sa[r][c] = A[(m < M_IMG ? m : 0) * CDIM + cc + c];
            sb[r][c] = B[(n0 + r) * CDIM + cc + c];
        }
        __syncthreads();
#pragma unroll
        for (int c = 0; c < 32; c++) {
            float a = sa[ki][c];
#pragma unroll
            for (int j = 0; j < 16; j++) acc[j] += a * sb[kpb + j][c];
        }
        __syncthreads();
    }
    int m = m0 + ki;
    if (m < M_IMG) {
        bool ma = mask_val(maskA, m, is_u8);
#pragma unroll
        for (int j = 0; j < 16; j++) {
            int n = n0 + kpb + j;
            bool ok = ma && mask_val(maskB, n, is_u8);
            sim[m * N_PCD + n] = ok ? acc[j] : NEG_INF;
        }
    }
}

// ---- top-3 helpers (values only, multiplicity preserved) ----
__device__ __forceinline__ void top3_insert(float v, float& t0, float& t1, float& t2) {
    if (v > t0) { t2 = t1; t1 = t0; t0 = v; }
    else if (v > t1) { t2 = t1; t1 = v; }
    else if (v > t2) { t2 = v; }
}

__device__ __forceinline__ void top3_merge(float a0, float a1, float a2,
                                           float b0, float b1, float b2,
                                           float& x0, float& x1, float& x2) {
    if (a0 >= b0) {
        x0 = a0;
        if (a1 >= b0) { x1 = a1; x2 = (a2 >= b0) ? a2 : b0; }
        else          { x1 = b0; x2 = (a1 >= b1) ? a1 : b1; }
    } else {
        x0 = b0;
        if (b1 >= a0) { x1 = b1; x2 = (b2 >= a0) ? b2 : a0; }
        else          { x1 = a0; x2 = (b1 >= a1) ? b1 : a1; }
    }
}

// =====================================================================
// Kernel B1: per-row 3rd largest. grid(1008)x256, 4 loads/thread.
// =====================================================================
__global__ void row_kth_kernel(const float* __restrict__ sim,
                               float* __restrict__ row_kth) {
    __shared__ float st[256][3];
    const int tid = threadIdx.x;
    const float* r = sim + (size_t)blockIdx.x * N_PCD;
    float t0 = NEG_INF, t1 = NEG_INF, t2 = NEG_INF;
#pragma unroll
    for (int e = 0; e < 4; e++) top3_insert(r[e * 256 + tid], t0, t1, t2);
    st[tid][0] = t0; st[tid][1] = t1; st[tid][2] = t2;
    __syncthreads();
    for (int s = 128; s > 0; s >>= 1) {
        if (tid < s) {
            float x0, x1, x2;
            top3_merge(st[tid][0], st[tid][1], st[tid][2],
                       st[tid + s][0], st[tid + s][1], st[tid + s][2],
                       x0, x1, x2);
            st[tid][0] = x0; st[tid][1] = x1; st[tid][2] = x2;
        }
        __syncthreads();
    }
    if (tid == 0) row_kth[blockIdx.x] = st[0][2];
}

// =====================================================================
// Kernel B2: column partial top-3. grid(16 col-stripes, 21 row-chunks)x256.
// Block covers 64 cols x 48 rows; thread = (column lane, row-group of 4).
// 12 independent coalesced loads/thread -> latency overlapped.
// Partials: colp[3][21][1024] (SoA for coalesced merge reads).
// =====================================================================
__global__ void col_partial_kernel(const float* __restrict__ sim,
                                   float* __restrict__ colp) {
    __shared__ float st[256][3];
    const int tid = threadIdx.x;
    const int c = tid & 63, rr = tid >> 6;
    const int col = blockIdx.x * 64 + c;
    const int r0 = blockIdx.y * 48;
    float t0 = NEG_INF, t1 = NEG_INF, t2 = NEG_INF;
#pragma unroll
    for (int k = 0; k < 12; k++) {
        float v = sim[(size_t)(r0 + rr + 4 * k) * N_PCD + col];
        top3_insert(v, t0, t1, t2);
    }
    st[tid][0] = t0; st[tid][1] = t1; st[tid][2] = t2;
    __syncthreads();
    if (tid < 128) {
        float x0, x1, x2;
        top3_merge(st[tid][0], st[tid][1], st[tid][2],
                   st[tid + 128][0], st[tid + 128][1], st[tid + 128][2],
                   x0, x1, x2);
        st[tid][0] = x0; st[tid][1] = x1; st[tid][2] = x2;
    }
    __syncthreads();
    if (tid < 64) {
        float x0, x1, x2;
        top3_merge(st[tid][0], st[tid][1], st[tid][2],
                   st[tid + 64][0], st[tid + 64][1], st[tid + 64][2],
                   x0, x1, x2);
        const int base = blockIdx.y * N_PCD + col;
        colp[base] = x0;
        colp[NCHUNK * N_PCD + base] = x1;
        colp[2 * NCHUNK * N_PCD + base] = x2;
    }
}

// Kernel B3: merge 21 column partials -> col 3rd largest. grid(4)x256.
__global__ void col_merge_kernel(const float* __restrict__ colp,
                                 float* __restrict__ col_kth) {
    const int col = blockIdx.x * 256 + threadIdx.x;
    float t0 = colp[col];
    float t1 = colp[NCHUNK * N_PCD + col];
    float t2 = colp[2 * NCHUNK * N_PCD + col];
#pragma unroll
    for (int ch = 1; ch < NCHUNK; ch++) {
        float b0 = colp[ch * N_PCD + col];
        float b1 = colp[NCHUNK * N_PCD + ch * N_PCD + col];
        float b2 = colp[2 * NCHUNK * N_PCD + ch * N_PCD + col];
        float x0, x1, x2;
        top3_merge(t0, t1, t2, b0, b1, b2, x0, x1, x2);
        t0 = x0; t1 = x1; t2 = x2;
    }
    col_kth[col] = t2;
}

// Kernel D: compact mutual candidates. grid(4032)x256
__global__ void compact_kernel(const float* __restrict__ sim,
                               const float* __restrict__ row_kth,
                               const float* __restrict__ col_kth,
                               unsigned long long* __restrict__ cand,
                               int* __restrict__ count) {
    int g = blockIdx.x * 256 + threadIdx.x;
    if (g >= M_IMG * N_PCD) return;
    int m = g >> 10, n = g & 1023;
    float v = sim[g];
    if (v > 0.f && v >= row_kth[m] && v >= col_kth[n]) {
        int pos = atomicAdd(count, 1);
        if (pos < CAND_CAP) {
            unsigned int u = __float_as_uint(v);
            unsigned int mono = (u & 0x80000000u) ? ~u : (u | 0x80000000u); // ascending map
            cand[pos] = ((unsigned long long)(~mono) << 32) | (unsigned int)g; // asc sort => val desc, idx asc
        }
    }
}

// =====================================================================
// Kernel E1: candidate rank via counting (keys are UNIQUE: distinct flat
// idx in low 32 bits => rank is an exact permutation; ascending packed key
// = (value desc, idx asc), matching lax.top_k tie-break). grid(16,16)x256.
// =====================================================================
__global__ void cand_rank_kernel(const unsigned long long* __restrict__ cand,
                                 const int* __restrict__ count,
                                 unsigned int* __restrict__ cnt2) {
    __shared__ unsigned long long s_k[256];
    const int tid = threadIdx.x;
    int K = *count; if (K > CAND_CAP) K = CAND_CAP;
    const int j0 = blockIdx.y * 256;
    if (j0 >= K) return;                        // uniform: whole chunk empty
    int j = j0 + tid;
    s_k[tid] = (j < K) ? cand[j] : 0xFFFFFFFFFFFFFFFFull;
    __syncthreads();
    const int i = blockIdx.x * 256 + tid;
    if (i >= K) return;
    const unsigned long long my = cand[i];
    unsigned int less = 0;
#pragma unroll 8
    for (int t = 0; t < 256; t++) less += (s_k[t] < my);
    if (less) atomicAdd(&cnt2[i], less);
}

// Kernel E2: select rank<256 into sel_idx (order irrelevant: final out[]
// depends only on the selected SET). grid(16)x256.
__global__ void cand_select_kernel(const unsigned long long* __restrict__ cand,
                                   const int* __restrict__ count,
                                   const unsigned int* __restrict__ cnt2,
                                   int* __restrict__ sel_idx,
                                   int* __restrict__ selK) {
    int K = *count; if (K > CAND_CAP) K = CAND_CAP;
    const int i = blockIdx.x * 256 + threadIdx.x;
    if (i == 0) *selK = (K < NUM_CORR) ? K : NUM_CORR;
    if (i < K) {
        unsigned int r = cnt2[i];
        if (r < NUM_CORR) sel_idx[r] = (int)(cand[i] & 0xFFFFFFFFull);
    }
}

// =====================================================================
// Kernel F: fine matching, one block per correspondence. grid(256)x256
// =====================================================================
__global__ void fine_kernel(const float* __restrict__ img_f,   // [76800,256]
                            const float* __restrict__ pcd_f,   // [30000,256]
                            const int* __restrict__ img_knn,   // [1008,64]
                            const int* __restrict__ pcd_knn,   // [1024,64]
                            const void* __restrict__ pcd_msk,  // [1024,64] bool
                            const int* __restrict__ flag,
                            const int* __restrict__ sel_idx,
                            const int* __restrict__ selK_ptr,
                            unsigned int* __restrict__ keys) { // [16384]
    const int ci = blockIdx.x, tid = threadIdx.x;
    const int selK = *selK_ptr;
    if (ci >= selK) {
        if (tid < KI) keys[ci * KI + tid] = SENT_KEY;
        return;
    }
    __shared__ int s_ik[KI], s_pk[KP];
    __shared__ unsigned char s_mk[KP];
    __shared__ float s_a[64][33], s_b[64][33];
    __shared__ float s_sim[64][65];
    __shared__ int s_rb[64], s_cb[64];
    __shared__ float s_rv[64];

    int flat = sel_idx[ci];
    int gi = flat >> 10, pi = flat & 1023;
    if (tid < 64) {
        const int is_u8 = (*flag != 0);
        s_ik[tid] = img_knn[gi * KI + tid];
        s_pk[tid] = pcd_knn[pi * KP + tid];
        s_mk[tid] = mask_val(pcd_msk, pi * KP + tid, is_u8) ? 1 : 0;
    }
    __syncthreads();

    const int ki = tid >> 2, kpb = (tid & 3) << 4;
    float acc[16];
#pragma unroll
    for (int j = 0; j < 16; j++) acc[j] = 0.f;

    for (int cc = 0; cc < CDIM; cc += 32) {
        for (int e = tid; e < 64 * 32; e += 256) {
            int r = e >> 5, c = e & 31;
            s_a[r][c] = img_f[(size_t)s_ik[r] * CDIM + cc + c];
            s_b[r][c] = pcd_f[(size_t)s_pk[r] * CDIM + cc + c];
        }
        __syncthreads();
#pragma unroll
        for (int c = 0; c < 32; c++) {
            float a = s_a[ki][c];
#pragma unroll
            for (int j = 0; j < 16; j++) acc[j] += a * s_b[kpb + j][c];
        }
        __syncthreads();
    }
#pragma unroll
    for (int j = 0; j < 16; j++) {
        int kp = kpb + j;
        s_sim[ki][kp] = (s_mk[kp] != 0) ? acc[j] : NEG_INF;
    }
    __syncthreads();

    if (tid < 64) {              // row argmax over kp (first-max semantics)
        float best = NEG_INF; int bi = 0;
        for (int kp = 0; kp < 64; kp++) {
            float v = s_sim[tid][kp];
            if (v > best) { best = v; bi = kp; }
        }
        s_rb[tid] = bi; s_rv[tid] = best;
    } else if (tid < 128) {      // col argmax over ki
        int kp = tid - 64;
        float best = NEG_INF; int bi = 0;
        for (int k2 = 0; k2 < 64; k2++) {
            float v = s_sim[k2][kp];
            if (v > best) { best = v; bi = k2; }
        }
        s_cb[kp] = bi;
    }
    __syncthreads();

    if (tid < 64) {
        int rb = s_rb[tid];
        float rv = s_rv[tid];
        bool sel = (s_cb[rb] == tid) && (rv > 0.f);   // mutual top-1 + finite + >FINE_THR
        unsigned int key = sel
            ? ((unsigned int)s_ik[tid] * KEY_MOD + (unsigned int)s_pk[rb])
            : SENT_KEY;
        keys[ci * KI + tid] = key;
    }
}

// =====================================================================
// Kernel G1: chunked rank partial counts. grid(64 my, 64 other)x256.
// cnt[i] += (less<<16) | eq_before  (packed u32; field totals < 2^16)
// =====================================================================
__global__ void rank_count_kernel(const unsigned int* __restrict__ keys,
                                  unsigned int* __restrict__ cnt) {
    __shared__ unsigned int s_k[256];
    const int tid = threadIdx.x;
    const int bi = blockIdx.x, bj = blockIdx.y;
    const int i = bi * 256 + tid;
    const unsigned int myKey = keys[i];
    s_k[tid] = keys[bj * 256 + tid];
    __syncthreads();

    unsigned int less = 0, eqb = 0;
    if (bj < bi) {
#pragma unroll 8
        for (int j = 0; j < 256; j++) {
            unsigned int k = s_k[j];
            less += (k < myKey);
            eqb += (k == myKey);
        }
    } else if (bj == bi) {
#pragma unroll 8
        for (int j = 0; j < 256; j++) {
            unsigned int k = s_k[j];
            less += (k < myKey);
            eqb += (k == myKey) & (j < tid);
        }
    } else {
#pragma unroll 8
        for (int j = 0; j < 256; j++) {
            unsigned int k = s_k[j];
            less += (k < myKey);
        }
    }
    atomicAdd(&cnt[i], (less << 16) | eqb);
}

// Kernel G2: unpack rank, first-occurrence; write scored output. grid(64)x256
__global__ void rank_out_kernel(const unsigned int* __restrict__ keys,
                                const unsigned int* __restrict__ cnt,
                                const float* __restrict__ img_f,
                                const float* __restrict__ pcd_f,
                                float* __restrict__ out) {
    const int i = blockIdx.x * 256 + threadIdx.x;
    const unsigned int myKey = keys[i];
    const unsigned int v = cnt[i];
    const int rank = (int)(v >> 16) + (int)(v & 0xFFFFu);
    unsigned int ic = myKey / KEY_MOD;
    unsigned int pc = myKey - ic * KEY_MOD;
    float score = 0.f;
    if ((v & 0xFFFFu) == 0 && ic < (unsigned)NI_F) {
        const float4* a = (const float4*)(img_f + (size_t)ic * CDIM);
        const float4* b = (const float4*)(pcd_f + (size_t)pc * CDIM);
        float s = 0.f;
#pragma unroll 4
        for (int c = 0; c < CDIM / 4; c++) {
            float4 x = a[c], y = b[c];
            s += x.x * y.x + x.y * y.y + x.z * y.z + x.w * y.w;
        }
        score = s;
    }
    out[rank] = score;
}

// =====================================================================
extern "C" void kernel_launch(void* const* d_in, const int* in_sizes, int n_in,
                              void* d_out, int out_size, void* d_ws, size_t ws_size,
                              hipStream_t stream) {
    const float* img_c = (const float*)d_in[0];
    const float* pcd_c = (const float*)d_in[1];
    const float* img_f = (const float*)d_in[2];
    const float* pcd_f = (const float*)d_in[3];
    const void* img_mask = d_in[4];
    const void* pcd_mask = d_in[5];
    const int* img_knn = (const int*)d_in[6];
    const int* pcd_knn = (const int*)d_in[7];
    const void* pcd_knn_msk = d_in[8];
    float* out = (float*)d_out;

    // ---- workspace layout ----
    char* w = (char*)d_ws;
    size_t off = 0;
    float* sim = (float*)(w + off);            off += (size_t)M_IMG * N_PCD * 4; // 4,128,768
    float* row_kth = (float*)(w + off);        off += M_IMG * 4;
    float* col_kth = (float*)(w + off);        off += N_PCD * 4;
    int* count = (int*)(w + off);              off += 4;
    int* selK = (int*)(w + off);               off += 4;
    int* boolflag = (int*)(w + off);           off += 4;
    off = (off + 7) & ~(size_t)7;
    unsigned long long* cand = (unsigned long long*)(w + off); off += CAND_CAP * 8;
    int* sel_idx = (int*)(w + off);            off += NUM_CORR * 4;
    unsigned int* keys = (unsigned int*)(w + off); off += NPAIR * 4;
    unsigned int* cnt = (unsigned int*)(w + off);  off += NPAIR * 4;   // dedup ranks
    unsigned int* cnt2 = (unsigned int*)(w + off); off += CAND_CAP * 4; // cand ranks
    float* colp = (float*)(w + off);           off += 3 * NCHUNK * N_PCD * 4; // 258KB

    hipMemsetAsync(count, 0, 12, stream);                        // count + selK + boolflag
    hipMemsetAsync(cnt, 0, (NPAIR + CAND_CAP) * 4, stream);      // cnt + cnt2 (contiguous)

    detect_bool_kernel<<<16, 256, 0, stream>>>((const unsigned int*)pcd_knn_msk, boolflag);
    coarse_sim_kernel<<<dim3(16, 16), 256, 0, stream>>>(img_c, pcd_c, img_mask, pcd_mask,
                                                        boolflag, sim);
    row_kth_kernel<<<M_IMG, 256, 0, stream>>>(sim, row_kth);
    col_partial_kernel<<<dim3(16, NCHUNK), 256, 0, stream>>>(sim, colp);
    col_merge_kernel<<<4, 256, 0, stream>>>(colp, col_kth);
    compact_kernel<<<(M_IMG * N_PCD) / 256, 256, 0, stream>>>(sim, row_kth, col_kth, cand, count);
    cand_rank_kernel<<<dim3(16, 16), 256, 0, stream>>>(cand, count, cnt2);
    cand_select_kernel<<<16, 256, 0, stream>>>(cand, count, cnt2, sel_idx, selK);
    fine_kernel<<<NUM_CORR, 256, 0, stream>>>(img_f, pcd_f, img_knn, pcd_knn, pcd_knn_msk,
                                              boolflag, sel_idx, selK, keys);
    rank_count_kernel<<<dim3(64, 64), 256, 0, stream>>>(keys, cnt);
    rank_out_kernel<<<NPAIR / 256, 256, 0, stream>>>(keys, cnt, img_f, pcd_f, out);
}

// Round 7
// 330.322 us; speedup vs baseline: 1.8568x; 1.1564x over previous
//
#include <hip/hip_runtime.h>
#include <hip/hip_bf16.h>

// ---- problem constants ----
#define M_IMG 1008
#define N_PCD 1024
#define CDIM  256
#define NI_F  76800
#define NP_F  30000
#define KI    64
#define KP    64
#define NUM_CORR 256
#define NPAIR (NUM_CORR * KI)       // 16384
#define CAND_CAP 4096
#define KEY_MOD 30001u
#define SENT_KEY (76800u * 30001u + 30000u)   // 2,304,106,800 < 2^32

#define NCHUNK 21                   // 21 row-chunks x 48 rows = 1008
#define NEG_INF (-__builtin_inff())

// bool inputs may arrive as uint8 (numpy bool) or int32 (harness "integer")
// layouts. Detected at runtime; *flag != 0 means uint8.
__device__ __forceinline__ bool mask_val(const void* p, int i, int is_u8) {
    return is_u8 ? (((const unsigned char*)p)[i] != 0)
                 : (((const int*)p)[i] != 0);
}

// Kernel 0: detect bool layout from pcd_knn_msk (65536 elements, ~90% true).
// u8 layout: upper 3 bytes of a u32 view often nonzero; i32 0/1 layout: never.
__global__ void detect_bool_kernel(const unsigned int* __restrict__ p,
                                   int* __restrict__ flag) {
    __shared__ int s_cnt;
    if (threadIdx.x == 0) s_cnt = 0;
    __syncthreads();
    unsigned int x = p[blockIdx.x * 256 + threadIdx.x];
    if (x & 0xFFFFFF00u) atomicAdd(&s_cnt, 1);
    __syncthreads();
    if (threadIdx.x == 0 && s_cnt != 0) atomicAdd(flag, 1);
}

// =====================================================================
// Shared 64x64x256 fp32 microkernel layout: c-major LDS tiles, 4x4
// register tile per thread (16 threads x 16 threads). Per c-iteration:
// 2x ds_read_b128 + 16 FMA (was 17 scalar ds_read_b32 + 16 FMA).
// Row padded to 68 floats: 272 B = 16-aligned for b128; read bank
// aliasing is 2-way (free, m136).
// =====================================================================

// Kernel A: coarse sim = img_c @ pcd_c^T, masked to -inf.  grid(16,16)x256
__global__ void coarse_sim_kernel(const float* __restrict__ A,   // [1008,256]
                                  const float* __restrict__ B,   // [1024,256]
                                  const void* __restrict__ maskA,
                                  const void* __restrict__ maskB,
                                  const int* __restrict__ flag,
                                  float* __restrict__ sim) {     // [1008,1024]
    __shared__ __align__(16) float s_a[32][68];
    __shared__ __align__(16) float s_b[32][68];
    const int is_u8 = (*flag != 0);
    const int m0 = blockIdx.y * 64, n0 = blockIdx.x * 64;
    const int tid = threadIdx.x;
    const int tx = tid & 15, ty = tid >> 4;
    float acc[4][4];
#pragma unroll
    for (int r = 0; r < 4; r++)
#pragma unroll
        for (int j = 0; j < 4; j++) acc[r][j] = 0.f;

    for (int cc = 0; cc < CDIM; cc += 32) {
        for (int e = tid; e < 64 * 32; e += 256) {
            int r = e >> 5, c = e & 31;
            int m = m0 + r;
            s_a[c][r] = A[(m < M_IMG ? m : 0) * CDIM + cc + c];
            s_b[c][r] = B[(n0 + r) * CDIM + cc + c];
        }
        __syncthreads();
#pragma unroll 8
        for (int c = 0; c < 32; c++) {
            float4 av = *(const float4*)&s_a[c][ty * 4];
            float4 bv = *(const float4*)&s_b[c][tx * 4];
            float ar[4] = {av.x, av.y, av.z, av.w};
            float br[4] = {bv.x, bv.y, bv.z, bv.w};
#pragma unroll
            for (int r = 0; r < 4; r++)
#pragma unroll
                for (int j = 0; j < 4; j++) acc[r][j] += ar[r] * br[j];
        }
        __syncthreads();
    }
#pragma unroll
    for (int r = 0; r < 4; r++) {
        int m = m0 + ty * 4 + r;
        if (m < M_IMG) {
            bool ma = mask_val(maskA, m, is_u8);
#pragma unroll
            for (int j = 0; j < 4; j++) {
                int n = n0 + tx * 4 + j;
                bool ok = ma && mask_val(maskB, n, is_u8);
                sim[m * N_PCD + n] = ok ? acc[r][j] : NEG_INF;
            }
        }
    }
}

// ---- top-3 helpers (values only, multiplicity preserved) ----
__device__ __forceinline__ void top3_insert(float v, float& t0, float& t1, float& t2) {
    if (v > t0) { t2 = t1; t1 = t0; t0 = v; }
    else if (v > t1) { t2 = t1; t1 = v; }
    else if (v > t2) { t2 = v; }
}

__device__ __forceinline__ void top3_merge(float a0, float a1, float a2,
                                           float b0, float b1, float b2,
                                           float& x0, float& x1, float& x2) {
    if (a0 >= b0) {
        x0 = a0;
        if (a1 >= b0) { x1 = a1; x2 = (a2 >= b0) ? a2 : b0; }
        else          { x1 = b0; x2 = (a1 >= b1) ? a1 : b1; }
    } else {
        x0 = b0;
        if (b1 >= a0) { x1 = b1; x2 = (b2 >= a0) ? b2 : a0; }
        else          { x1 = a0; x2 = (b1 >= a1) ? b1 : a1; }
    }
}

// =====================================================================
// Kernel B: fused row + column-partial top-3. grid(1008 + 16*21)x256.
// Blocks [0,1008): one row each (4 loads/thread).
// Blocks [1008,1344): 64 cols x 48 rows each; 12 independent coalesced
// loads/thread. Partials colp[3][21][1024] (SoA).
// =====================================================================
__global__ void kth_kernel(const float* __restrict__ sim,
                           float* __restrict__ row_kth,
                           float* __restrict__ colp) {
    __shared__ float st[256][3];
    const int tid = threadIdx.x;
    if (blockIdx.x < M_IMG) {
        const float* r = sim + (size_t)blockIdx.x * N_PCD;
        float t0 = NEG_INF, t1 = NEG_INF, t2 = NEG_INF;
#pragma unroll
        for (int e = 0; e < 4; e++) top3_insert(r[e * 256 + tid], t0, t1, t2);
        st[tid][0] = t0; st[tid][1] = t1; st[tid][2] = t2;
        __syncthreads();
        for (int s = 128; s > 0; s >>= 1) {
            if (tid < s) {
                float x0, x1, x2;
                top3_merge(st[tid][0], st[tid][1], st[tid][2],
                           st[tid + s][0], st[tid + s][1], st[tid + s][2],
                           x0, x1, x2);
                st[tid][0] = x0; st[tid][1] = x1; st[tid][2] = x2;
            }
            __syncthreads();
        }
        if (tid == 0) row_kth[blockIdx.x] = st[0][2];
    } else {
        const int b = blockIdx.x - M_IMG;        // 0..335
        const int bx = b & 15, by = b >> 4;      // stripe, row-chunk
        const int c = tid & 63, rr = tid >> 6;
        const int col = bx * 64 + c;
        const int r0 = by * 48;
        float t0 = NEG_INF, t1 = NEG_INF, t2 = NEG_INF;
#pragma unroll
        for (int k = 0; k < 12; k++) {
            float v = sim[(size_t)(r0 + rr + 4 * k) * N_PCD + col];
            top3_insert(v, t0, t1, t2);
        }
        st[tid][0] = t0; st[tid][1] = t1; st[tid][2] = t2;
        __syncthreads();
        if (tid < 128) {
            float x0, x1, x2;
            top3_merge(st[tid][0], st[tid][1], st[tid][2],
                       st[tid + 128][0], st[tid + 128][1], st[tid + 128][2],
                       x0, x1, x2);
            st[tid][0] = x0; st[tid][1] = x1; st[tid][2] = x2;
        }
        __syncthreads();
        if (tid < 64) {
            float x0, x1, x2;
            top3_merge(st[tid][0], st[tid][1], st[tid][2],
                       st[tid + 64][0], st[tid + 64][1], st[tid + 64][2],
                       x0, x1, x2);
            const int base = by * N_PCD + col;
            colp[base] = x0;
            colp[NCHUNK * N_PCD + base] = x1;
            colp[2 * NCHUNK * N_PCD + base] = x2;
        }
    }
}

// Kernel B3: merge 21 column partials -> col 3rd largest. grid(4)x256.
__global__ void col_merge_kernel(const float* __restrict__ colp,
                                 float* __restrict__ col_kth) {
    const int col = blockIdx.x * 256 + threadIdx.x;
    float t0 = colp[col];
    float t1 = colp[NCHUNK * N_PCD + col];
    float t2 = colp[2 * NCHUNK * N_PCD + col];
#pragma unroll
    for (int ch = 1; ch < NCHUNK; ch++) {
        float b0 = colp[ch * N_PCD + col];
        float b1 = colp[NCHUNK * N_PCD + ch * N_PCD + col];
        float b2 = colp[2 * NCHUNK * N_PCD + ch * N_PCD + col];
        float x0, x1, x2;
        top3_merge(t0, t1, t2, b0, b1, b2, x0, x1, x2);
        t0 = x0; t1 = x1; t2 = x2;
    }
    col_kth[col] = t2;
}

// Kernel D: compact mutual candidates. grid(4032)x256
__global__ void compact_kernel(const float* __restrict__ sim,
                               const float* __restrict__ row_kth,
                               const float* __restrict__ col_kth,
                               unsigned long long* __restrict__ cand,
                               int* __restrict__ count) {
    int g = blockIdx.x * 256 + threadIdx.x;
    if (g >= M_IMG * N_PCD) return;
    int m = g >> 10, n = g & 1023;
    float v = sim[g];
    if (v > 0.f && v >= row_kth[m] && v >= col_kth[n]) {
        int pos = atomicAdd(count, 1);
        if (pos < CAND_CAP) {
            unsigned int u = __float_as_uint(v);
            unsigned int mono = (u & 0x80000000u) ? ~u : (u | 0x80000000u); // ascending map
            cand[pos] = ((unsigned long long)(~mono) << 32) | (unsigned int)g; // asc sort => val desc, idx asc
        }
    }
}

// =====================================================================
// Kernel E1: candidate rank via counting (keys are UNIQUE: distinct flat
// idx in low 32 bits => rank is an exact permutation; ascending packed key
// = (value desc, idx asc), matching lax.top_k tie-break). grid(16,16)x256.
// =====================================================================
__global__ void cand_rank_kernel(const unsigned long long* __restrict__ cand,
                                 const int* __restrict__ count,
                                 unsigned int* __restrict__ cnt2) {
    __shared__ unsigned long long s_k[256];
    const int tid = threadIdx.x;
    int K = *count; if (K > CAND_CAP) K = CAND_CAP;
    const int j0 = blockIdx.y * 256;
    if (j0 >= K) return;                        // uniform: whole chunk empty
    int j = j0 + tid;
    s_k[tid] = (j < K) ? cand[j] : 0xFFFFFFFFFFFFFFFFull;
    __syncthreads();
    const int i = blockIdx.x * 256 + tid;
    if (i >= K) return;
    const unsigned long long my = cand[i];
    unsigned int less = 0;
#pragma unroll 8
    for (int t = 0; t < 256; t++) less += (s_k[t] < my);
    if (less) atomicAdd(&cnt2[i], less);
}

// Kernel E2: select rank<256 into sel_idx (order irrelevant: final out[]
// depends only on the selected SET). grid(16)x256.
__global__ void cand_select_kernel(const unsigned long long* __restrict__ cand,
                                   const int* __restrict__ count,
                                   const unsigned int* __restrict__ cnt2,
                                   int* __restrict__ sel_idx,
                                   int* __restrict__ selK) {
    int K = *count; if (K > CAND_CAP) K = CAND_CAP;
    const int i = blockIdx.x * 256 + threadIdx.x;
    if (i == 0) *selK = (K < NUM_CORR) ? K : NUM_CORR;
    if (i < K) {
        unsigned int r = cnt2[i];
        if (r < NUM_CORR) sel_idx[r] = (int)(cand[i] & 0xFFFFFFFFull);
    }
}

// =====================================================================
// Kernel F: fine matching, one block per correspondence. grid(256)x256.
// Same 4x4-register-tile microkernel as coarse_sim.
// =====================================================================
__global__ void fine_kernel(const float* __restrict__ img_f,   // [76800,256]
                            const float* __restrict__ pcd_f,   // [30000,256]
                            const int* __restrict__ img_knn,   // [1008,64]
                            const int* __restrict__ pcd_knn,   // [1024,64]
                            const void* __restrict__ pcd_msk,  // [1024,64] bool
                            const int* __restrict__ flag,
                            const int* __restrict__ sel_idx,
                            const int* __restrict__ selK_ptr,
                            unsigned int* __restrict__ keys) { // [16384]
    const int ci = blockIdx.x, tid = threadIdx.x;
    const int selK = *selK_ptr;
    if (ci >= selK) {
        if (tid < KI) keys[ci * KI + tid] = SENT_KEY;
        return;
    }
    __shared__ int s_ik[KI], s_pk[KP];
    __shared__ unsigned char s_mk[KP];
    __shared__ __align__(16) float s_a[32][68];
    __shared__ __align__(16) float s_b[32][68];
    __shared__ float s_sim[64][65];
    __shared__ int s_rb[64], s_cb[64];
    __shared__ float s_rv[64];

    int flat = sel_idx[ci];
    int gi = flat >> 10, pi = flat & 1023;
    if (tid < 64) {
        const int is_u8 = (*flag != 0);
        s_ik[tid] = img_knn[gi * KI + tid];
        s_pk[tid] = pcd_knn[pi * KP + tid];
        s_mk[tid] = mask_val(pcd_msk, pi * KP + tid, is_u8) ? 1 : 0;
    }
    __syncthreads();

    const int tx = tid & 15, ty = tid >> 4;
    float acc[4][4];
#pragma unroll
    for (int r = 0; r < 4; r++)
#pragma unroll
        for (int j = 0; j < 4; j++) acc[r][j] = 0.f;

    for (int cc = 0; cc < CDIM; cc += 32) {
        for (int e = tid; e < 64 * 32; e += 256) {
            int r = e >> 5, c = e & 31;
            s_a[c][r] = img_f[(size_t)s_ik[r] * CDIM + cc + c];
            s_b[c][r] = pcd_f[(size_t)s_pk[r] * CDIM + cc + c];
        }
        __syncthreads();
#pragma unroll 8
        for (int c = 0; c < 32; c++) {
            float4 av = *(const float4*)&s_a[c][ty * 4];
            float4 bv = *(const float4*)&s_b[c][tx * 4];
            float ar[4] = {av.x, av.y, av.z, av.w};
            float br[4] = {bv.x, bv.y, bv.z, bv.w};
#pragma unroll
            for (int r = 0; r < 4; r++)
#pragma unroll
                for (int j = 0; j < 4; j++) acc[r][j] += ar[r] * br[j];
        }
        __syncthreads();
    }
#pragma unroll
    for (int r = 0; r < 4; r++) {
        int row = ty * 4 + r;
#pragma unroll
        for (int j = 0; j < 4; j++) {
            int kp = tx * 4 + j;
            s_sim[row][kp] = (s_mk[kp] != 0) ? acc[r][j] : NEG_INF;
        }
    }
    __syncthreads();

    if (tid < 64) {              // row argmax over kp (first-max semantics)
        float best = NEG_INF; int bi = 0;
        for (int kp = 0; kp < 64; kp++) {
            float v = s_sim[tid][kp];
            if (v > best) { best = v; bi = kp; }
        }
        s_rb[tid] = bi; s_rv[tid] = best;
    } else if (tid < 128) {      // col argmax over ki
        int kp = tid - 64;
        float best = NEG_INF; int bi = 0;
        for (int k2 = 0; k2 < 64; k2++) {
            float v = s_sim[k2][kp];
            if (v > best) { best = v; bi = k2; }
        }
        s_cb[kp] = bi;
    }
    __syncthreads();

    if (tid < 64) {
        int rb = s_rb[tid];
        float rv = s_rv[tid];
        bool sel = (s_cb[rb] == tid) && (rv > 0.f);   // mutual top-1 + finite + >FINE_THR
        unsigned int key = sel
            ? ((unsigned int)s_ik[tid] * KEY_MOD + (unsigned int)s_pk[rb])
            : SENT_KEY;
        keys[ci * KI + tid] = key;
    }
}

// =====================================================================
// Kernel G1: chunked rank partial counts. grid(64 my, 64 other)x256.
// cnt[i] += (less<<16) | eq_before  (packed u32; field totals < 2^16)
// =====================================================================
__global__ void rank_count_kernel(const unsigned int* __restrict__ keys,
                                  unsigned int* __restrict__ cnt) {
    __shared__ unsigned int s_k[256];
    const int tid = threadIdx.x;
    const int bi = blockIdx.x, bj = blockIdx.y;
    const int i = bi * 256 + tid;
    const unsigned int myKey = keys[i];
    s_k[tid] = keys[bj * 256 + tid];
    __syncthreads();

    unsigned int less = 0, eqb = 0;
    if (bj < bi) {
#pragma unroll 8
        for (int j = 0; j < 256; j++) {
            unsigned int k = s_k[j];
            less += (k < myKey);
            eqb += (k == myKey);
        }
    } else if (bj == bi) {
#pragma unroll 8
        for (int j = 0; j < 256; j++) {
            unsigned int k = s_k[j];
            less += (k < myKey);
            eqb += (k == myKey) & (j < tid);
        }
    } else {
#pragma unroll 8
        for (int j = 0; j < 256; j++) {
            unsigned int k = s_k[j];
            less += (k < myKey);
        }
    }
    atomicAdd(&cnt[i], (less << 16) | eqb);
}

// Kernel G2: unpack rank, first-occurrence; write scored output. grid(64)x256
__global__ void rank_out_kernel(const unsigned int* __restrict__ keys,
                                const unsigned int* __restrict__ cnt,
                                const float* __restrict__ img_f,
                                const float* __restrict__ pcd_f,
                                float* __restrict__ out) {
    const int i = blockIdx.x * 256 + threadIdx.x;
    const unsigned int myKey = keys[i];
    const unsigned int v = cnt[i];
    const int rank = (int)(v >> 16) + (int)(v & 0xFFFFu);
    unsigned int ic = myKey / KEY_MOD;
    unsigned int pc = myKey - ic * KEY_MOD;
    float score = 0.f;
    if ((v & 0xFFFFu) == 0 && ic < (unsigned)NI_F) {
        const float4* a = (const float4*)(img_f + (size_t)ic * CDIM);
        const float4* b = (const float4*)(pcd_f + (size_t)pc * CDIM);
        float s = 0.f;
#pragma unroll 8
        for (int c = 0; c < CDIM / 4; c++) {
            float4 x = a[c], y = b[c];
            s += x.x * y.x + x.y * y.y + x.z * y.z + x.w * y.w;
        }
        score = s;
    }
    out[rank] = score;
}

// =====================================================================
extern "C" void kernel_launch(void* const* d_in, const int* in_sizes, int n_in,
                              void* d_out, int out_size, void* d_ws, size_t ws_size,
                              hipStream_t stream) {
    const float* img_c = (const float*)d_in[0];
    const float* pcd_c = (const float*)d_in[1];
    const float* img_f = (const float*)d_in[2];
    const float* pcd_f = (const float*)d_in[3];
    const void* img_mask = d_in[4];
    const void* pcd_mask = d_in[5];
    const int* img_knn = (const int*)d_in[6];
    const int* pcd_knn = (const int*)d_in[7];
    const void* pcd_knn_msk = d_in[8];
    float* out = (float*)d_out;

    // ---- workspace layout ----
    char* w = (char*)d_ws;
    size_t off = 0;
    float* sim = (float*)(w + off);            off += (size_t)M_IMG * N_PCD * 4; // 4,128,768
    float* row_kth = (float*)(w + off);        off += M_IMG * 4;
    float* col_kth = (float*)(w + off);        off += N_PCD * 4;
    int* count = (int*)(w + off);              off += 4;
    int* selK = (int*)(w + off);               off += 4;
    int* boolflag = (int*)(w + off);           off += 4;
    off = (off + 7) & ~(size_t)7;
    unsigned long long* cand = (unsigned long long*)(w + off); off += CAND_CAP * 8;
    int* sel_idx = (int*)(w + off);            off += NUM_CORR * 4;
    unsigned int* keys = (unsigned int*)(w + off); off += NPAIR * 4;
    unsigned int* cnt = (unsigned int*)(w + off);  off += NPAIR * 4;   // dedup ranks
    unsigned int* cnt2 = (unsigned int*)(w + off); off += CAND_CAP * 4; // cand ranks
    float* colp = (float*)(w + off);           off += 3 * NCHUNK * N_PCD * 4; // 258KB

    hipMemsetAsync(count, 0, 12, stream);                        // count + selK + boolflag
    hipMemsetAsync(cnt, 0, (NPAIR + CAND_CAP) * 4, stream);      // cnt + cnt2 (contiguous)

    detect_bool_kernel<<<16, 256, 0, stream>>>((const unsigned int*)pcd_knn_msk, boolflag);
    coarse_sim_kernel<<<dim3(16, 16), 256, 0, stream>>>(img_c, pcd_c, img_mask, pcd_mask,
                                                        boolflag, sim);
    kth_kernel<<<M_IMG + 16 * NCHUNK, 256, 0, stream>>>(sim, row_kth, colp);
    col_merge_kernel<<<4, 256, 0, stream>>>(colp, col_kth);
    compact_kernel<<<(M_IMG * N_PCD) / 256, 256, 0, stream>>>(sim, row_kth, col_kth, cand, count);
    cand_rank_kernel<<<dim3(16, 16), 256, 0, stream>>>(cand, count, cnt2);
    cand_select_kernel<<<16, 256, 0, stream>>>(cand, count, cnt2, sel_idx, selK);
    fine_kernel<<<NUM_CORR, 256, 0, stream>>>(img_f, pcd_f, img_knn, pcd_knn, pcd_knn_msk,
                                              boolflag, sel_idx, selK, keys);
    rank_count_kernel<<<dim3(64, 64), 256, 0, stream>>>(keys, cnt);
    rank_out_kernel<<<NPAIR / 256, 256, 0, stream>>>(keys, cnt, img_f, pcd_f, out);
}

// Round 8
// 281.693 us; speedup vs baseline: 2.1773x; 1.1726x over previous
//
#include <hip/hip_runtime.h>
#include <hip/hip_bf16.h>

// ---- problem constants ----
#define M_IMG 1008
#define N_PCD 1024
#define CDIM  256
#define NI_F  76800
#define NP_F  30000
#define KI    64
#define KP    64
#define NUM_CORR 256
#define NPAIR (NUM_CORR * KI)       // 16384
#define CAND_CAP 4096
#define KEY_MOD 30001u
#define SENT_KEY (76800u * 30001u + 30000u)   // 2,304,106,800 < 2^32

#define NCHUNK 21                   // 21 row-chunks x 48 rows = 1008
#define NEG_INF (-__builtin_inff())

// bool inputs may arrive as uint8 (numpy bool) or int32 (harness "integer")
// layouts. Detected at runtime; *flag != 0 means uint8.
__device__ __forceinline__ bool mask_val(const void* p, int i, int is_u8) {
    return is_u8 ? (((const unsigned char*)p)[i] != 0)
                 : (((const int*)p)[i] != 0);
}

// Kernel 0: detect bool layout from pcd_knn_msk (65536 elements, ~90% true).
// u8 layout: upper 3 bytes of a u32 view often nonzero; i32 0/1 layout: never.
__global__ void detect_bool_kernel(const unsigned int* __restrict__ p,
                                   int* __restrict__ flag) {
    __shared__ int s_cnt;
    if (threadIdx.x == 0) s_cnt = 0;
    __syncthreads();
    unsigned int x = p[blockIdx.x * 256 + threadIdx.x];
    if (x & 0xFFFFFF00u) atomicAdd(&s_cnt, 1);
    __syncthreads();
    if (threadIdx.x == 0 && s_cnt != 0) atomicAdd(flag, 1);
}

// =====================================================================
// Shared 64x64x256 fp32 microkernel: c-major LDS tiles (row padded to 68
// floats = 16B-aligned b128 reads, 2-way read aliasing = free), 4x4
// register tile per thread. K-loop is software-pipelined: chunk ci+1 is
// register-prefetched during chunk ci's compute (1 block/CU -> latency
// must hide via ILP, not TLP). Staging decomposition: c = tid&31
// (thread-invariant), r = (tid>>5) + 8k -> 8 fixed rows per matrix.
// =====================================================================

// Kernel A: coarse sim = img_c @ pcd_c^T, masked to -inf.  grid(16,16)x256
__global__ void coarse_sim_kernel(const float* __restrict__ A,   // [1008,256]
                                  const float* __restrict__ B,   // [1024,256]
                                  const void* __restrict__ maskA,
                                  const void* __restrict__ maskB,
                                  const int* __restrict__ flag,
                                  float* __restrict__ sim) {     // [1008,1024]
    __shared__ __align__(16) float s_a[32][68];
    __shared__ __align__(16) float s_b[32][68];
    const int is_u8 = (*flag != 0);
    const int m0 = blockIdx.y * 64, n0 = blockIdx.x * 64;
    const int tid = threadIdx.x;
    const int tx = tid & 15, ty = tid >> 4;
    const int c_lane = tid & 31;
    const int r_base = tid >> 5;                 // 0..7

    const float* pa[8];
    const float* pb[8];
#pragma unroll
    for (int k = 0; k < 8; k++) {
        int m = m0 + r_base + 8 * k;
        pa[k] = A + (size_t)(m < M_IMG ? m : 0) * CDIM + c_lane;
        pb[k] = B + (size_t)(n0 + r_base + 8 * k) * CDIM + c_lane;
    }

    float ra[8], rb[8];
#pragma unroll
    for (int k = 0; k < 8; k++) { ra[k] = pa[k][0]; rb[k] = pb[k][0]; }
#pragma unroll
    for (int k = 0; k < 8; k++) {
        s_a[c_lane][r_base + 8 * k] = ra[k];
        s_b[c_lane][r_base + 8 * k] = rb[k];
    }
    __syncthreads();

    float acc[4][4];
#pragma unroll
    for (int r = 0; r < 4; r++)
#pragma unroll
        for (int j = 0; j < 4; j++) acc[r][j] = 0.f;

    for (int ci = 0; ci < 8; ci++) {
        if (ci < 7) {
            const int cc = (ci + 1) * 32;
#pragma unroll
            for (int k = 0; k < 8; k++) { ra[k] = pa[k][cc]; rb[k] = pb[k][cc]; }
        }
#pragma unroll 8
        for (int c = 0; c < 32; c++) {
            float4 av = *(const float4*)&s_a[c][ty * 4];
            float4 bv = *(const float4*)&s_b[c][tx * 4];
            float ar[4] = {av.x, av.y, av.z, av.w};
            float br[4] = {bv.x, bv.y, bv.z, bv.w};
#pragma unroll
            for (int r = 0; r < 4; r++)
#pragma unroll
                for (int j = 0; j < 4; j++) acc[r][j] += ar[r] * br[j];
        }
        __syncthreads();
        if (ci < 7) {
#pragma unroll
            for (int k = 0; k < 8; k++) {
                s_a[c_lane][r_base + 8 * k] = ra[k];
                s_b[c_lane][r_base + 8 * k] = rb[k];
            }
            __syncthreads();
        }
    }
#pragma unroll
    for (int r = 0; r < 4; r++) {
        int m = m0 + ty * 4 + r;
        if (m < M_IMG) {
            bool ma = mask_val(maskA, m, is_u8);
#pragma unroll
            for (int j = 0; j < 4; j++) {
                int n = n0 + tx * 4 + j;
                bool ok = ma && mask_val(maskB, n, is_u8);
                sim[m * N_PCD + n] = ok ? acc[r][j] : NEG_INF;
            }
        }
    }
}

// ---- top-3 helpers (values only, multiplicity preserved) ----
__device__ __forceinline__ void top3_insert(float v, float& t0, float& t1, float& t2) {
    if (v > t0) { t2 = t1; t1 = t0; t0 = v; }
    else if (v > t1) { t2 = t1; t1 = v; }
    else if (v > t2) { t2 = v; }
}

__device__ __forceinline__ void top3_merge(float a0, float a1, float a2,
                                           float b0, float b1, float b2,
                                           float& x0, float& x1, float& x2) {
    if (a0 >= b0) {
        x0 = a0;
        if (a1 >= b0) { x1 = a1; x2 = (a2 >= b0) ? a2 : b0; }
        else          { x1 = b0; x2 = (a1 >= b1) ? a1 : b1; }
    } else {
        x0 = b0;
        if (b1 >= a0) { x1 = b1; x2 = (b2 >= a0) ? b2 : a0; }
        else          { x1 = a0; x2 = (b1 >= a1) ? b1 : a1; }
    }
}

// =====================================================================
// Kernel B: fused row + column-partial top-3. grid(1008 + 16*21)x256.
// =====================================================================
__global__ void kth_kernel(const float* __restrict__ sim,
                           float* __restrict__ row_kth,
                           float* __restrict__ colp) {
    __shared__ float st[256][3];
    const int tid = threadIdx.x;
    if (blockIdx.x < M_IMG) {
        const float* r = sim + (size_t)blockIdx.x * N_PCD;
        float t0 = NEG_INF, t1 = NEG_INF, t2 = NEG_INF;
#pragma unroll
        for (int e = 0; e < 4; e++) top3_insert(r[e * 256 + tid], t0, t1, t2);
        st[tid][0] = t0; st[tid][1] = t1; st[tid][2] = t2;
        __syncthreads();
        for (int s = 128; s > 0; s >>= 1) {
            if (tid < s) {
                float x0, x1, x2;
                top3_merge(st[tid][0], st[tid][1], st[tid][2],
                           st[tid + s][0], st[tid + s][1], st[tid + s][2],
                           x0, x1, x2);
                st[tid][0] = x0; st[tid][1] = x1; st[tid][2] = x2;
            }
            __syncthreads();
        }
        if (tid == 0) row_kth[blockIdx.x] = st[0][2];
    } else {
        const int b = blockIdx.x - M_IMG;        // 0..335
        const int bx = b & 15, by = b >> 4;      // stripe, row-chunk
        const int c = tid & 63, rr = tid >> 6;
        const int col = bx * 64 + c;
        const int r0 = by * 48;
        float t0 = NEG_INF, t1 = NEG_INF, t2 = NEG_INF;
#pragma unroll
        for (int k = 0; k < 12; k++) {
            float v = sim[(size_t)(r0 + rr + 4 * k) * N_PCD + col];
            top3_insert(v, t0, t1, t2);
        }
        st[tid][0] = t0; st[tid][1] = t1; st[tid][2] = t2;
        __syncthreads();
        if (tid < 128) {
            float x0, x1, x2;
            top3_merge(st[tid][0], st[tid][1], st[tid][2],
                       st[tid + 128][0], st[tid + 128][1], st[tid + 128][2],
                       x0, x1, x2);
            st[tid][0] = x0; st[tid][1] = x1; st[tid][2] = x2;
        }
        __syncthreads();
        if (tid < 64) {
            float x0, x1, x2;
            top3_merge(st[tid][0], st[tid][1], st[tid][2],
                       st[tid + 64][0], st[tid + 64][1], st[tid + 64][2],
                       x0, x1, x2);
            const int base = by * N_PCD + col;
            colp[base] = x0;
            colp[NCHUNK * N_PCD + base] = x1;
            colp[2 * NCHUNK * N_PCD + base] = x2;
        }
    }
}

// Kernel B3: merge 21 column partials -> col 3rd largest. grid(4)x256.
__global__ void col_merge_kernel(const float* __restrict__ colp,
                                 float* __restrict__ col_kth) {
    const int col = blockIdx.x * 256 + threadIdx.x;
    float t0 = colp[col];
    float t1 = colp[NCHUNK * N_PCD + col];
    float t2 = colp[2 * NCHUNK * N_PCD + col];
#pragma unroll
    for (int ch = 1; ch < NCHUNK; ch++) {
        float b0 = colp[ch * N_PCD + col];
        float b1 = colp[NCHUNK * N_PCD + ch * N_PCD + col];
        float b2 = colp[2 * NCHUNK * N_PCD + ch * N_PCD + col];
        float x0, x1, x2;
        top3_merge(t0, t1, t2, b0, b1, b2, x0, x1, x2);
        t0 = x0; t1 = x1; t2 = x2;
    }
    col_kth[col] = t2;
}

// Kernel D: compact mutual candidates. grid(4032)x256
__global__ void compact_kernel(const float* __restrict__ sim,
                               const float* __restrict__ row_kth,
                               const float* __restrict__ col_kth,
                               unsigned long long* __restrict__ cand,
                               int* __restrict__ count) {
    int g = blockIdx.x * 256 + threadIdx.x;
    if (g >= M_IMG * N_PCD) return;
    int m = g >> 10, n = g & 1023;
    float v = sim[g];
    if (v > 0.f && v >= row_kth[m] && v >= col_kth[n]) {
        int pos = atomicAdd(count, 1);
        if (pos < CAND_CAP) {
            unsigned int u = __float_as_uint(v);
            unsigned int mono = (u & 0x80000000u) ? ~u : (u | 0x80000000u); // ascending map
            cand[pos] = ((unsigned long long)(~mono) << 32) | (unsigned int)g; // asc sort => val desc, idx asc
        }
    }
}

// =====================================================================
// Kernel E1: candidate rank via counting (keys are UNIQUE: distinct flat
// idx in low 32 bits => rank is an exact permutation; ascending packed key
// = (value desc, idx asc), matching lax.top_k tie-break). grid(16,16)x256.
// =====================================================================
__global__ void cand_rank_kernel(const unsigned long long* __restrict__ cand,
                                 const int* __restrict__ count,
                                 unsigned int* __restrict__ cnt2) {
    __shared__ unsigned long long s_k[256];
    const int tid = threadIdx.x;
    int K = *count; if (K > CAND_CAP) K = CAND_CAP;
    const int j0 = blockIdx.y * 256;
    if (j0 >= K) return;                        // uniform: whole chunk empty
    int j = j0 + tid;
    s_k[tid] = (j < K) ? cand[j] : 0xFFFFFFFFFFFFFFFFull;
    __syncthreads();
    const int i = blockIdx.x * 256 + tid;
    if (i >= K) return;
    const unsigned long long my = cand[i];
    unsigned int less = 0;
#pragma unroll 8
    for (int t = 0; t < 256; t++) less += (s_k[t] < my);
    if (less) atomicAdd(&cnt2[i], less);
}

// Kernel E2: select rank<256 into sel_idx (order irrelevant: final out[]
// depends only on the selected SET). grid(16)x256.
__global__ void cand_select_kernel(const unsigned long long* __restrict__ cand,
                                   const int* __restrict__ count,
                                   const unsigned int* __restrict__ cnt2,
                                   int* __restrict__ sel_idx,
                                   int* __restrict__ selK) {
    int K = *count; if (K > CAND_CAP) K = CAND_CAP;
    const int i = blockIdx.x * 256 + threadIdx.x;
    if (i == 0) *selK = (K < NUM_CORR) ? K : NUM_CORR;
    if (i < K) {
        unsigned int r = cnt2[i];
        if (r < NUM_CORR) sel_idx[r] = (int)(cand[i] & 0xFFFFFFFFull);
    }
}

// =====================================================================
// Kernel F: fine matching, one block per correspondence. grid(256)x256.
// Same pipelined 4x4-register-tile microkernel as coarse_sim, with
// gathered rows (knn indices loaded to registers once).
// =====================================================================
__global__ void fine_kernel(const float* __restrict__ img_f,   // [76800,256]
                            const float* __restrict__ pcd_f,   // [30000,256]
                            const int* __restrict__ img_knn,   // [1008,64]
                            const int* __restrict__ pcd_knn,   // [1024,64]
                            const void* __restrict__ pcd_msk,  // [1024,64] bool
                            const int* __restrict__ flag,
                            const int* __restrict__ sel_idx,
                            const int* __restrict__ selK_ptr,
                            unsigned int* __restrict__ keys) { // [16384]
    const int ci = blockIdx.x, tid = threadIdx.x;
    const int selK = *selK_ptr;
    if (ci >= selK) {
        if (tid < KI) keys[ci * KI + tid] = SENT_KEY;
        return;
    }
    __shared__ int s_ik[KI], s_pk[KP];
    __shared__ unsigned char s_mk[KP];
    __shared__ __align__(16) float s_a[32][68];
    __shared__ __align__(16) float s_b[32][68];
    __shared__ float s_sim[64][65];
    __shared__ int s_rb[64], s_cb[64];
    __shared__ float s_rv[64];

    int flat = sel_idx[ci];
    int gi = flat >> 10, pi = flat & 1023;
    if (tid < 64) {
        const int is_u8 = (*flag != 0);
        s_ik[tid] = img_knn[gi * KI + tid];
        s_pk[tid] = pcd_knn[pi * KP + tid];
        s_mk[tid] = mask_val(pcd_msk, pi * KP + tid, is_u8) ? 1 : 0;
    }
    __syncthreads();

    const int tx = tid & 15, ty = tid >> 4;
    const int c_lane = tid & 31;
    const int r_base = tid >> 5;                 // 0..7

    const float* pa[8];
    const float* pb[8];
#pragma unroll
    for (int k = 0; k < 8; k++) {
        pa[k] = img_f + (size_t)s_ik[r_base + 8 * k] * CDIM + c_lane;
        pb[k] = pcd_f + (size_t)s_pk[r_base + 8 * k] * CDIM + c_lane;
    }

    float ra[8], rb[8];
#pragma unroll
    for (int k = 0; k < 8; k++) { ra[k] = pa[k][0]; rb[k] = pb[k][0]; }
#pragma unroll
    for (int k = 0; k < 8; k++) {
        s_a[c_lane][r_base + 8 * k] = ra[k];
        s_b[c_lane][r_base + 8 * k] = rb[k];
    }
    __syncthreads();

    float acc[4][4];
#pragma unroll
    for (int r = 0; r < 4; r++)
#pragma unroll
        for (int j = 0; j < 4; j++) acc[r][j] = 0.f;

    for (int cit = 0; cit < 8; cit++) {
        if (cit < 7) {
            const int cc = (cit + 1) * 32;
#pragma unroll
            for (int k = 0; k < 8; k++) { ra[k] = pa[k][cc]; rb[k] = pb[k][cc]; }
        }
#pragma unroll 8
        for (int c = 0; c < 32; c++) {
            float4 av = *(const float4*)&s_a[c][ty * 4];
            float4 bv = *(const float4*)&s_b[c][tx * 4];
            float ar[4] = {av.x, av.y, av.z, av.w};
            float br[4] = {bv.x, bv.y, bv.z, bv.w};
#pragma unroll
            for (int r = 0; r < 4; r++)
#pragma unroll
                for (int j = 0; j < 4; j++) acc[r][j] += ar[r] * br[j];
        }
        __syncthreads();
        if (cit < 7) {
#pragma unroll
            for (int k = 0; k < 8; k++) {
                s_a[c_lane][r_base + 8 * k] = ra[k];
                s_b[c_lane][r_base + 8 * k] = rb[k];
            }
            __syncthreads();
        }
    }
#pragma unroll
    for (int r = 0; r < 4; r++) {
        int row = ty * 4 + r;
#pragma unroll
        for (int j = 0; j < 4; j++) {
            int kp = tx * 4 + j;
            s_sim[row][kp] = (s_mk[kp] != 0) ? acc[r][j] : NEG_INF;
        }
    }
    __syncthreads();

    if (tid < 64) {              // row argmax over kp (first-max semantics)
        float best = NEG_INF; int bi = 0;
        for (int kp = 0; kp < 64; kp++) {
            float v = s_sim[tid][kp];
            if (v > best) { best = v; bi = kp; }
        }
        s_rb[tid] = bi; s_rv[tid] = best;
    } else if (tid < 128) {      // col argmax over ki
        int kp = tid - 64;
        float best = NEG_INF; int bi = 0;
        for (int k2 = 0; k2 < 64; k2++) {
            float v = s_sim[k2][kp];
            if (v > best) { best = v; bi = k2; }
        }
        s_cb[kp] = bi;
    }
    __syncthreads();

    if (tid < 64) {
        int rb2 = s_rb[tid];
        float rv = s_rv[tid];
        bool sel = (s_cb[rb2] == tid) && (rv > 0.f);  // mutual top-1 + finite + >FINE_THR
        unsigned int key = sel
            ? ((unsigned int)s_ik[tid] * KEY_MOD + (unsigned int)s_pk[rb2])
            : SENT_KEY;
        keys[ci * KI + tid] = key;
    }
}

// =====================================================================
// Kernel G1: chunked rank partial counts. grid(64 my, 64 other)x256.
// cnt[i] += (less<<16) | eq_before  (packed u32; field totals < 2^16)
// =====================================================================
__global__ void rank_count_kernel(const unsigned int* __restrict__ keys,
                                  unsigned int* __restrict__ cnt) {
    __shared__ unsigned int s_k[256];
    const int tid = threadIdx.x;
    const int bi = blockIdx.x, bj = blockIdx.y;
    const int i = bi * 256 + tid;
    const unsigned int myKey = keys[i];
    s_k[tid] = keys[bj * 256 + tid];
    __syncthreads();

    unsigned int less = 0, eqb = 0;
    if (bj < bi) {
#pragma unroll 8
        for (int j = 0; j < 256; j++) {
            unsigned int k = s_k[j];
            less += (k < myKey);
            eqb += (k == myKey);
        }
    } else if (bj == bi) {
#pragma unroll 8
        for (int j = 0; j < 256; j++) {
            unsigned int k = s_k[j];
            less += (k < myKey);
            eqb += (k == myKey) & (j < tid);
        }
    } else {
#pragma unroll 8
        for (int j = 0; j < 256; j++) {
            unsigned int k = s_k[j];
            less += (k < myKey);
        }
    }
    atomicAdd(&cnt[i], (less << 16) | eqb);
}

// Kernel G2: unpack rank, first-occurrence; write scored output. grid(64)x256
__global__ void rank_out_kernel(const unsigned int* __restrict__ keys,
                                const unsigned int* __restrict__ cnt,
                                const float* __restrict__ img_f,
                                const float* __restrict__ pcd_f,
                                float* __restrict__ out) {
    const int i = blockIdx.x * 256 + threadIdx.x;
    const unsigned int myKey = keys[i];
    const unsigned int v = cnt[i];
    const int rank = (int)(v >> 16) + (int)(v & 0xFFFFu);
    unsigned int ic = myKey / KEY_MOD;
    unsigned int pc = myKey - ic * KEY_MOD;
    float score = 0.f;
    if ((v & 0xFFFFu) == 0 && ic < (unsigned)NI_F) {
        const float4* a = (const float4*)(img_f + (size_t)ic * CDIM);
        const float4* b = (const float4*)(pcd_f + (size_t)pc * CDIM);
        float s = 0.f;
#pragma unroll 8
        for (int c = 0; c < CDIM / 4; c++) {
            float4 x = a[c], y = b[c];
            s += x.x * y.x + x.y * y.y + x.z * y.z + x.w * y.w;
        }
        score = s;
    }
    out[rank] = score;
}

// =====================================================================
extern "C" void kernel_launch(void* const* d_in, const int* in_sizes, int n_in,
                              void* d_out, int out_size, void* d_ws, size_t ws_size,
                              hipStream_t stream) {
    const float* img_c = (const float*)d_in[0];
    const float* pcd_c = (const float*)d_in[1];
    const float* img_f = (const float*)d_in[2];
    const float* pcd_f = (const float*)d_in[3];
    const void* img_mask = d_in[4];
    const void* pcd_mask = d_in[5];
    const int* img_knn = (const int*)d_in[6];
    const int* pcd_knn = (const int*)d_in[7];
    const void* pcd_knn_msk = d_in[8];
    float* out = (float*)d_out;

    // ---- workspace layout ----
    char* w = (char*)d_ws;
    size_t off = 0;
    float* sim = (float*)(w + off);            off += (size_t)M_IMG * N_PCD * 4; // 4,128,768
    float* row_kth = (float*)(w + off);        off += M_IMG * 4;
    float* col_kth = (float*)(w + off);        off += N_PCD * 4;
    int* count = (int*)(w + off);              off += 4;
    int* selK = (int*)(w + off);               off += 4;
    int* boolflag = (int*)(w + off);           off += 4;
    off = (off + 7) & ~(size_t)7;
    unsigned long long* cand = (unsigned long long*)(w + off); off += CAND_CAP * 8;
    int* sel_idx = (int*)(w + off);            off += NUM_CORR * 4;
    unsigned int* keys = (unsigned int*)(w + off); off += NPAIR * 4;
    unsigned int* cnt = (unsigned int*)(w + off);  off += NPAIR * 4;   // dedup ranks
    unsigned int* cnt2 = (unsigned int*)(w + off); off += CAND_CAP * 4; // cand ranks
    float* colp = (float*)(w + off);           off += 3 * NCHUNK * N_PCD * 4; // 258KB

    hipMemsetAsync(count, 0, 12, stream);                        // count + selK + boolflag
    hipMemsetAsync(cnt, 0, (NPAIR + CAND_CAP) * 4, stream);      // cnt + cnt2 (contiguous)

    detect_bool_kernel<<<16, 256, 0, stream>>>((const unsigned int*)pcd_knn_msk, boolflag);
    coarse_sim_kernel<<<dim3(16, 16), 256, 0, stream>>>(img_c, pcd_c, img_mask, pcd_mask,
                                                        boolflag, sim);
    kth_kernel<<<M_IMG + 16 * NCHUNK, 256, 0, stream>>>(sim, row_kth, colp);
    col_merge_kernel<<<4, 256, 0, stream>>>(colp, col_kth);
    compact_kernel<<<(M_IMG * N_PCD) / 256, 256, 0, stream>>>(sim, row_kth, col_kth, cand, count);
    cand_rank_kernel<<<dim3(16, 16), 256, 0, stream>>>(cand, count, cnt2);
    cand_select_kernel<<<16, 256, 0, stream>>>(cand, count, cnt2, sel_idx, selK);
    fine_kernel<<<NUM_CORR, 256, 0, stream>>>(img_f, pcd_f, img_knn, pcd_knn, pcd_knn_msk,
                                              boolflag, sel_idx, selK, keys);
    rank_count_kernel<<<dim3(64, 64), 256, 0, stream>>>(keys, cnt);
    rank_out_kernel<<<NPAIR / 256, 256, 0, stream>>>(keys, cnt, img_f, pcd_f, out);
}

// Round 9
// 274.109 us; speedup vs baseline: 2.2376x; 1.0277x over previous
//
#include <hip/hip_runtime.h>
#include <hip/hip_bf16.h>

// ---- problem constants ----
#define M_IMG 1008
#define N_PCD 1024
#define CDIM  256
#define NI_F  76800
#define NP_F  30000
#define KI    64
#define KP    64
#define NUM_CORR 256
#define NPAIR (NUM_CORR * KI)       // 16384
#define CAND_CAP 4096
#define KEY_MOD 30001u
#define SENT_KEY (76800u * 30001u + 30000u)   // 2,304,106,800 < 2^32

#define NCHUNK 21                   // 21 row-chunks x 48 rows = 1008
#define NEG_INF (-__builtin_inff())

// bool inputs may arrive as uint8 (numpy bool) or int32 (harness "integer")
// layouts. Detected at runtime; *flag != 0 means uint8.
__device__ __forceinline__ bool mask_val(const void* p, int i, int is_u8) {
    return is_u8 ? (((const unsigned char*)p)[i] != 0)
                 : (((const int*)p)[i] != 0);
}

// Kernel 0: detect bool layout from pcd_knn_msk (65536 elements, ~90% true).
__global__ void detect_bool_kernel(const unsigned int* __restrict__ p,
                                   int* __restrict__ flag) {
    __shared__ int s_cnt;
    if (threadIdx.x == 0) s_cnt = 0;
    __syncthreads();
    unsigned int x = p[blockIdx.x * 256 + threadIdx.x];
    if (x & 0xFFFFFF00u) atomicAdd(&s_cnt, 1);
    __syncthreads();
    if (threadIdx.x == 0 && s_cnt != 0) atomicAdd(flag, 1);
}

// =====================================================================
// GEMM microkernels: c-major LDS tiles, software-pipelined K-loop
// (register-prefetch chunk ci+1 during chunk ci compute). R8: raised
// TLP — coarse runs 32x64 tiles (512 blocks = 2 blocks/CU); fine runs
// 512 threads (2 waves/SIMD). Per c-iter/thread: b64(A) + b128(B) + 8 FMA.
// Accumulation order over c unchanged -> bitwise-stable outputs.
// =====================================================================

// Kernel A: coarse sim = img_c @ pcd_c^T, masked to -inf.  grid(16,32)x256
__global__ void coarse_sim_kernel(const float* __restrict__ A,   // [1008,256]
                                  const float* __restrict__ B,   // [1024,256]
                                  const void* __restrict__ maskA,
                                  const void* __restrict__ maskB,
                                  const int* __restrict__ flag,
                                  float* __restrict__ sim) {     // [1008,1024]
    __shared__ __align__(16) float s_a[32][36];  // 32 rows tile, 8B-aligned rows
    __shared__ __align__(16) float s_b[32][68];
    const int is_u8 = (*flag != 0);
    const int m0 = blockIdx.y * 32, n0 = blockIdx.x * 64;
    const int tid = threadIdx.x;
    const int tx = tid & 15, ty = tid >> 4;      // ty 0..15 -> 2 rows each
    const int c_lane = tid & 31;
    const int r_base = tid >> 5;                 // 0..7

    const float* pa[4];
    const float* pb[8];
#pragma unroll
    for (int k = 0; k < 4; k++) {
        int m = m0 + r_base + 8 * k;             // 0..31 within tile
        pa[k] = A + (size_t)(m < M_IMG ? m : 0) * CDIM + c_lane;
    }
#pragma unroll
    for (int k = 0; k < 8; k++)
        pb[k] = B + (size_t)(n0 + r_base + 8 * k) * CDIM + c_lane;

    float ra[4], rb[8];
#pragma unroll
    for (int k = 0; k < 4; k++) ra[k] = pa[k][0];
#pragma unroll
    for (int k = 0; k < 8; k++) rb[k] = pb[k][0];
#pragma unroll
    for (int k = 0; k < 4; k++) s_a[c_lane][r_base + 8 * k] = ra[k];
#pragma unroll
    for (int k = 0; k < 8; k++) s_b[c_lane][r_base + 8 * k] = rb[k];
    __syncthreads();

    float acc[2][4];
#pragma unroll
    for (int r = 0; r < 2; r++)
#pragma unroll
        for (int j = 0; j < 4; j++) acc[r][j] = 0.f;

    for (int cit = 0; cit < 8; cit++) {
        if (cit < 7) {
            const int cc = (cit + 1) * 32;
#pragma unroll
            for (int k = 0; k < 4; k++) ra[k] = pa[k][cc];
#pragma unroll
            for (int k = 0; k < 8; k++) rb[k] = pb[k][cc];
        }
#pragma unroll 8
        for (int c = 0; c < 32; c++) {
            float2 av = *(const float2*)&s_a[c][ty * 2];
            float4 bv = *(const float4*)&s_b[c][tx * 4];
            float ar[2] = {av.x, av.y};
            float br[4] = {bv.x, bv.y, bv.z, bv.w};
#pragma unroll
            for (int r = 0; r < 2; r++)
#pragma unroll
                for (int j = 0; j < 4; j++) acc[r][j] += ar[r] * br[j];
        }
        __syncthreads();
        if (cit < 7) {
#pragma unroll
            for (int k = 0; k < 4; k++) s_a[c_lane][r_base + 8 * k] = ra[k];
#pragma unroll
            for (int k = 0; k < 8; k++) s_b[c_lane][r_base + 8 * k] = rb[k];
            __syncthreads();
        }
    }
#pragma unroll
    for (int r = 0; r < 2; r++) {
        int m = m0 + ty * 2 + r;
        if (m < M_IMG) {
            bool ma = mask_val(maskA, m, is_u8);
#pragma unroll
            for (int j = 0; j < 4; j++) {
                int n = n0 + tx * 4 + j;
                bool ok = ma && mask_val(maskB, n, is_u8);
                sim[m * N_PCD + n] = ok ? acc[r][j] : NEG_INF;
            }
        }
    }
}

// ---- top-3 helpers (values only, multiplicity preserved) ----
__device__ __forceinline__ void top3_insert(float v, float& t0, float& t1, float& t2) {
    if (v > t0) { t2 = t1; t1 = t0; t0 = v; }
    else if (v > t1) { t2 = t1; t1 = v; }
    else if (v > t2) { t2 = v; }
}

__device__ __forceinline__ void top3_merge(float a0, float a1, float a2,
                                           float b0, float b1, float b2,
                                           float& x0, float& x1, float& x2) {
    if (a0 >= b0) {
        x0 = a0;
        if (a1 >= b0) { x1 = a1; x2 = (a2 >= b0) ? a2 : b0; }
        else          { x1 = b0; x2 = (a1 >= b1) ? a1 : b1; }
    } else {
        x0 = b0;
        if (b1 >= a0) { x1 = b1; x2 = (b2 >= a0) ? b2 : a0; }
        else          { x1 = a0; x2 = (b1 >= a1) ? b1 : a1; }
    }
}

// =====================================================================
// Kernel B: fused row + column-partial top-3. grid(1008 + 16*21)x256.
// =====================================================================
__global__ void kth_kernel(const float* __restrict__ sim,
                           float* __restrict__ row_kth,
                           float* __restrict__ colp) {
    __shared__ float st[256][3];
    const int tid = threadIdx.x;
    if (blockIdx.x < M_IMG) {
        const float* r = sim + (size_t)blockIdx.x * N_PCD;
        float t0 = NEG_INF, t1 = NEG_INF, t2 = NEG_INF;
#pragma unroll
        for (int e = 0; e < 4; e++) top3_insert(r[e * 256 + tid], t0, t1, t2);
        st[tid][0] = t0; st[tid][1] = t1; st[tid][2] = t2;
        __syncthreads();
        for (int s = 128; s > 0; s >>= 1) {
            if (tid < s) {
                float x0, x1, x2;
                top3_merge(st[tid][0], st[tid][1], st[tid][2],
                           st[tid + s][0], st[tid + s][1], st[tid + s][2],
                           x0, x1, x2);
                st[tid][0] = x0; st[tid][1] = x1; st[tid][2] = x2;
            }
            __syncthreads();
        }
        if (tid == 0) row_kth[blockIdx.x] = st[0][2];
    } else {
        const int b = blockIdx.x - M_IMG;        // 0..335
        const int bx = b & 15, by = b >> 4;      // stripe, row-chunk
        const int c = tid & 63, rr = tid >> 6;
        const int col = bx * 64 + c;
        const int r0 = by * 48;
        float t0 = NEG_INF, t1 = NEG_INF, t2 = NEG_INF;
#pragma unroll
        for (int k = 0; k < 12; k++) {
            float v = sim[(size_t)(r0 + rr + 4 * k) * N_PCD + col];
            top3_insert(v, t0, t1, t2);
        }
        st[tid][0] = t0; st[tid][1] = t1; st[tid][2] = t2;
        __syncthreads();
        if (tid < 128) {
            float x0, x1, x2;
            top3_merge(st[tid][0], st[tid][1], st[tid][2],
                       st[tid + 128][0], st[tid + 128][1], st[tid + 128][2],
                       x0, x1, x2);
            st[tid][0] = x0; st[tid][1] = x1; st[tid][2] = x2;
        }
        __syncthreads();
        if (tid < 64) {
            float x0, x1, x2;
            top3_merge(st[tid][0], st[tid][1], st[tid][2],
                       st[tid + 64][0], st[tid + 64][1], st[tid + 64][2],
                       x0, x1, x2);
            const int base = by * N_PCD + col;
            colp[base] = x0;
            colp[NCHUNK * N_PCD + base] = x1;
            colp[2 * NCHUNK * N_PCD + base] = x2;
        }
    }
}

// Kernel B3: merge 21 column partials -> col 3rd largest. grid(4)x256.
__global__ void col_merge_kernel(const float* __restrict__ colp,
                                 float* __restrict__ col_kth) {
    const int col = blockIdx.x * 256 + threadIdx.x;
    float t0 = colp[col];
    float t1 = colp[NCHUNK * N_PCD + col];
    float t2 = colp[2 * NCHUNK * N_PCD + col];
#pragma unroll
    for (int ch = 1; ch < NCHUNK; ch++) {
        float b0 = colp[ch * N_PCD + col];
        float b1 = colp[NCHUNK * N_PCD + ch * N_PCD + col];
        float b2 = colp[2 * NCHUNK * N_PCD + ch * N_PCD + col];
        float x0, x1, x2;
        top3_merge(t0, t1, t2, b0, b1, b2, x0, x1, x2);
        t0 = x0; t1 = x1; t2 = x2;
    }
    col_kth[col] = t2;
}

// Kernel D: compact mutual candidates. grid(4032)x256
__global__ void compact_kernel(const float* __restrict__ sim,
                               const float* __restrict__ row_kth,
                               const float* __restrict__ col_kth,
                               unsigned long long* __restrict__ cand,
                               int* __restrict__ count) {
    int g = blockIdx.x * 256 + threadIdx.x;
    if (g >= M_IMG * N_PCD) return;
    int m = g >> 10, n = g & 1023;
    float v = sim[g];
    if (v > 0.f && v >= row_kth[m] && v >= col_kth[n]) {
        int pos = atomicAdd(count, 1);
        if (pos < CAND_CAP) {
            unsigned int u = __float_as_uint(v);
            unsigned int mono = (u & 0x80000000u) ? ~u : (u | 0x80000000u); // ascending map
            cand[pos] = ((unsigned long long)(~mono) << 32) | (unsigned int)g; // asc sort => val desc, idx asc
        }
    }
}

// =====================================================================
// Kernel E1: candidate rank via counting (keys are UNIQUE). grid(16,16)x256.
// =====================================================================
__global__ void cand_rank_kernel(const unsigned long long* __restrict__ cand,
                                 const int* __restrict__ count,
                                 unsigned int* __restrict__ cnt2) {
    __shared__ unsigned long long s_k[256];
    const int tid = threadIdx.x;
    int K = *count; if (K > CAND_CAP) K = CAND_CAP;
    const int j0 = blockIdx.y * 256;
    if (j0 >= K) return;                        // uniform: whole chunk empty
    int j = j0 + tid;
    s_k[tid] = (j < K) ? cand[j] : 0xFFFFFFFFFFFFFFFFull;
    __syncthreads();
    const int i = blockIdx.x * 256 + tid;
    if (i >= K) return;
    const unsigned long long my = cand[i];
    unsigned int less = 0;
#pragma unroll 8
    for (int t = 0; t < 256; t++) less += (s_k[t] < my);
    if (less) atomicAdd(&cnt2[i], less);
}

// Kernel E2: select rank<256 into sel_idx (order irrelevant). grid(16)x256.
__global__ void cand_select_kernel(const unsigned long long* __restrict__ cand,
                                   const int* __restrict__ count,
                                   const unsigned int* __restrict__ cnt2,
                                   int* __restrict__ sel_idx,
                                   int* __restrict__ selK) {
    int K = *count; if (K > CAND_CAP) K = CAND_CAP;
    const int i = blockIdx.x * 256 + threadIdx.x;
    if (i == 0) *selK = (K < NUM_CORR) ? K : NUM_CORR;
    if (i < K) {
        unsigned int r = cnt2[i];
        if (r < NUM_CORR) sel_idx[r] = (int)(cand[i] & 0xFFFFFFFFull);
    }
}

// =====================================================================
// Kernel F: fine matching, one block per correspondence. grid(256)x512.
// 512 threads = 2 waves/SIMD for latency hiding; pipelined staging.
// =====================================================================
__global__ void fine_kernel(const float* __restrict__ img_f,   // [76800,256]
                            const float* __restrict__ pcd_f,   // [30000,256]
                            const int* __restrict__ img_knn,   // [1008,64]
                            const int* __restrict__ pcd_knn,   // [1024,64]
                            const void* __restrict__ pcd_msk,  // [1024,64] bool
                            const int* __restrict__ flag,
                            const int* __restrict__ sel_idx,
                            const int* __restrict__ selK_ptr,
                            unsigned int* __restrict__ keys) { // [16384]
    const int ci = blockIdx.x, tid = threadIdx.x;
    const int selK = *selK_ptr;
    if (ci >= selK) {
        if (tid < KI) keys[ci * KI + tid] = SENT_KEY;
        return;
    }
    __shared__ int s_ik[KI], s_pk[KP];
    __shared__ unsigned char s_mk[KP];
    __shared__ __align__(16) float s_a[32][68];
    __shared__ __align__(16) float s_b[32][68];
    __shared__ float s_sim[64][65];
    __shared__ int s_rb[64], s_cb[64];
    __shared__ float s_rv[64];

    int flat = sel_idx[ci];
    int gi = flat >> 10, pi = flat & 1023;
    if (tid < 64) {
        const int is_u8 = (*flag != 0);
        s_ik[tid] = img_knn[gi * KI + tid];
        s_pk[tid] = pcd_knn[pi * KP + tid];
        s_mk[tid] = mask_val(pcd_msk, pi * KP + tid, is_u8) ? 1 : 0;
    }
    __syncthreads();

    const int tx = tid & 15, tyy = tid >> 4;     // tyy 0..31 -> 2 rows each
    const int c_lane = tid & 31;
    const int r_base = tid >> 5;                 // 0..15 -> 4 rows each

    const float* pa[4];
    const float* pb[4];
#pragma unroll
    for (int k = 0; k < 4; k++) {
        pa[k] = img_f + (size_t)s_ik[r_base + 16 * k] * CDIM + c_lane;
        pb[k] = pcd_f + (size_t)s_pk[r_base + 16 * k] * CDIM + c_lane;
    }

    float ra[4], rb[4];
#pragma unroll
    for (int k = 0; k < 4; k++) { ra[k] = pa[k][0]; rb[k] = pb[k][0]; }
#pragma unroll
    for (int k = 0; k < 4; k++) {
        s_a[c_lane][r_base + 16 * k] = ra[k];
        s_b[c_lane][r_base + 16 * k] = rb[k];
    }
    __syncthreads();

    float acc[2][4];
#pragma unroll
    for (int r = 0; r < 2; r++)
#pragma unroll
        for (int j = 0; j < 4; j++) acc[r][j] = 0.f;

    for (int cit = 0; cit < 8; cit++) {
        if (cit < 7) {
            const int cc = (cit + 1) * 32;
#pragma unroll
            for (int k = 0; k < 4; k++) { ra[k] = pa[k][cc]; rb[k] = pb[k][cc]; }
        }
#pragma unroll 8
        for (int c = 0; c < 32; c++) {
            float2 av = *(const float2*)&s_a[c][tyy * 2];
            float4 bv = *(const float4*)&s_b[c][tx * 4];
            float ar[2] = {av.x, av.y};
            float br[4] = {bv.x, bv.y, bv.z, bv.w};
#pragma unroll
            for (int r = 0; r < 2; r++)
#pragma unroll
                for (int j = 0; j < 4; j++) acc[r][j] += ar[r] * br[j];
        }
        __syncthreads();
        if (cit < 7) {
#pragma unroll
            for (int k = 0; k < 4; k++) {
                s_a[c_lane][r_base + 16 * k] = ra[k];
                s_b[c_lane][r_base + 16 * k] = rb[k];
            }
            __syncthreads();
        }
    }
#pragma unroll
    for (int r = 0; r < 2; r++) {
        int row = tyy * 2 + r;
#pragma unroll
        for (int j = 0; j < 4; j++) {
            int kp = tx * 4 + j;
            s_sim[row][kp] = (s_mk[kp] != 0) ? acc[r][j] : NEG_INF;
        }
    }
    __syncthreads();

    if (tid < 64) {              // row argmax over kp (first-max semantics)
        float best = NEG_INF; int bi = 0;
        for (int kp = 0; kp < 64; kp++) {
            float v = s_sim[tid][kp];
            if (v > best) { best = v; bi = kp; }
        }
        s_rb[tid] = bi; s_rv[tid] = best;
    } else if (tid < 128) {      // col argmax over ki
        int kp = tid - 64;
        float best = NEG_INF; int bi = 0;
        for (int k2 = 0; k2 < 64; k2++) {
            float v = s_sim[k2][kp];
            if (v > best) { best = v; bi = k2; }
        }
        s_cb[kp] = bi;
    }
    __syncthreads();

    if (tid < 64) {
        int rb2 = s_rb[tid];
        float rv = s_rv[tid];
        bool sel = (s_cb[rb2] == tid) && (rv > 0.f);  // mutual top-1 + finite + >FINE_THR
        unsigned int key = sel
            ? ((unsigned int)s_ik[tid] * KEY_MOD + (unsigned int)s_pk[rb2])
            : SENT_KEY;
        keys[ci * KI + tid] = key;
    }
}

// =====================================================================
// Kernel G1: chunked rank partial counts. grid(64 my, 64 other)x256.
// cnt[i] += (less<<16) | eq_before  (packed u32; field totals < 2^16)
// =====================================================================
__global__ void rank_count_kernel(const unsigned int* __restrict__ keys,
                                  unsigned int* __restrict__ cnt) {
    __shared__ unsigned int s_k[256];
    const int tid = threadIdx.x;
    const int bi = blockIdx.x, bj = blockIdx.y;
    const int i = bi * 256 + tid;
    const unsigned int myKey = keys[i];
    s_k[tid] = keys[bj * 256 + tid];
    __syncthreads();

    unsigned int less = 0, eqb = 0;
    if (bj < bi) {
#pragma unroll 8
        for (int j = 0; j < 256; j++) {
            unsigned int k = s_k[j];
            less += (k < myKey);
            eqb += (k == myKey);
        }
    } else if (bj == bi) {
#pragma unroll 8
        for (int j = 0; j < 256; j++) {
            unsigned int k = s_k[j];
            less += (k < myKey);
            eqb += (k == myKey) & (j < tid);
        }
    } else {
#pragma unroll 8
        for (int j = 0; j < 256; j++) {
            unsigned int k = s_k[j];
            less += (k < myKey);
        }
    }
    atomicAdd(&cnt[i], (less << 16) | eqb);
}

// Kernel G2: unpack rank, first-occurrence; write scored output. grid(64)x256
__global__ void rank_out_kernel(const unsigned int* __restrict__ keys,
                                const unsigned int* __restrict__ cnt,
                                const float* __restrict__ img_f,
                                const float* __restrict__ pcd_f,
                                float* __restrict__ out) {
    const int i = blockIdx.x * 256 + threadIdx.x;
    const unsigned int myKey = keys[i];
    const unsigned int v = cnt[i];
    const int rank = (int)(v >> 16) + (int)(v & 0xFFFFu);
    unsigned int ic = myKey / KEY_MOD;
    unsigned int pc = myKey - ic * KEY_MOD;
    float score = 0.f;
    if ((v & 0xFFFFu) == 0 && ic < (unsigned)NI_F) {
        const float4* a = (const float4*)(img_f + (size_t)ic * CDIM);
        const float4* b = (const float4*)(pcd_f + (size_t)pc * CDIM);
        float s = 0.f;
#pragma unroll 8
        for (int c = 0; c < CDIM / 4; c++) {
            float4 x = a[c], y = b[c];
            s += x.x * y.x + x.y * y.y + x.z * y.z + x.w * y.w;
        }
        score = s;
    }
    out[rank] = score;
}

// =====================================================================
extern "C" void kernel_launch(void* const* d_in, const int* in_sizes, int n_in,
                              void* d_out, int out_size, void* d_ws, size_t ws_size,
                              hipStream_t stream) {
    const float* img_c = (const float*)d_in[0];
    const float* pcd_c = (const float*)d_in[1];
    const float* img_f = (const float*)d_in[2];
    const float* pcd_f = (const float*)d_in[3];
    const void* img_mask = d_in[4];
    const void* pcd_mask = d_in[5];
    const int* img_knn = (const int*)d_in[6];
    const int* pcd_knn = (const int*)d_in[7];
    const void* pcd_knn_msk = d_in[8];
    float* out = (float*)d_out;

    // ---- workspace layout ----
    char* w = (char*)d_ws;
    size_t off = 0;
    float* sim = (float*)(w + off);            off += (size_t)M_IMG * N_PCD * 4; // 4,128,768
    float* row_kth = (float*)(w + off);        off += M_IMG * 4;
    float* col_kth = (float*)(w + off);        off += N_PCD * 4;
    int* count = (int*)(w + off);              off += 4;
    int* selK = (int*)(w + off);               off += 4;
    int* boolflag = (int*)(w + off);           off += 4;
    off = (off + 7) & ~(size_t)7;
    unsigned long long* cand = (unsigned long long*)(w + off); off += CAND_CAP * 8;
    int* sel_idx = (int*)(w + off);            off += NUM_CORR * 4;
    unsigned int* keys = (unsigned int*)(w + off); off += NPAIR * 4;
    unsigned int* cnt = (unsigned int*)(w + off);  off += NPAIR * 4;   // dedup ranks
    unsigned int* cnt2 = (unsigned int*)(w + off); off += CAND_CAP * 4; // cand ranks
    float* colp = (float*)(w + off);           off += 3 * NCHUNK * N_PCD * 4; // 258KB

    hipMemsetAsync(count, 0, 12, stream);                        // count + selK + boolflag
    hipMemsetAsync(cnt, 0, (NPAIR + CAND_CAP) * 4, stream);      // cnt + cnt2 (contiguous)

    detect_bool_kernel<<<16, 256, 0, stream>>>((const unsigned int*)pcd_knn_msk, boolflag);
    coarse_sim_kernel<<<dim3(16, 32), 256, 0, stream>>>(img_c, pcd_c, img_mask, pcd_mask,
                                                        boolflag, sim);
    kth_kernel<<<M_IMG + 16 * NCHUNK, 256, 0, stream>>>(sim, row_kth, colp);
    col_merge_kernel<<<4, 256, 0, stream>>>(colp, col_kth);
    compact_kernel<<<(M_IMG * N_PCD) / 256, 256, 0, stream>>>(sim, row_kth, col_kth, cand, count);
    cand_rank_kernel<<<dim3(16, 16), 256, 0, stream>>>(cand, count, cnt2);
    cand_select_kernel<<<16, 256, 0, stream>>>(cand, count, cnt2, sel_idx, selK);
    fine_kernel<<<NUM_CORR, 512, 0, stream>>>(img_f, pcd_f, img_knn, pcd_knn, pcd_knn_msk,
                                              boolflag, sel_idx, selK, keys);
    rank_count_kernel<<<dim3(64, 64), 256, 0, stream>>>(keys, cnt);
    rank_out_kernel<<<NPAIR / 256, 256, 0, stream>>>(keys, cnt, img_f, pcd_f, out);
}